// Round 5
// baseline (346.235 us; speedup 1.0000x reference)
//
#include <hip/hip_runtime.h>
#include <hip/hip_fp16.h>

// ---------------- problem constants ----------------
constexpr int B_ = 256;        // batch
constexpr int K_ = 6144;       // block length
constexpr int NITER = 6;
constexpr int L_ = 6;          // window valid length -> C_=1024 chunks
constexpr int W0_ = 6;         // uniform-init warmup (iteration 0)
constexpr int C_ = K_ / L_;    // chunks = 1024
constexpr float LOG2E = 1.4426950408889634f;
constexpr float LN2   = 0.6931471805599453f;

static_assert(K_ % L_ == 0, "");
static_assert((L_ % 2) == 0 && (W0_ % 2) == 0, "");
static_assert(W0_ <= L_, "uniform-warmup trick requires W0 <= L");

#if __has_builtin(__builtin_amdgcn_exp2f)
#define EXP2F(x) __builtin_amdgcn_exp2f(x)
#else
#define EXP2F(x) exp2f(x)
#endif
#if __has_builtin(__builtin_amdgcn_logf)
#define LOG2F(x) __builtin_amdgcn_logf(x)
#else
#define LOG2F(x) log2f(x)
#endif
#if __has_builtin(__builtin_amdgcn_rcpf)
#define RCPF(x) __builtin_amdgcn_rcpf(x)
#else
#define RCPF(x) (1.0f / (x))
#endif

// ---- bf16 scalar helpers (RNE) ----
__device__ __forceinline__ float b2f(unsigned short u) {
  return __uint_as_float((unsigned)u << 16);
}
__device__ __forceinline__ unsigned short f2b(float f) {
  unsigned u = __float_as_uint(f);
  u += 0x7FFFu + ((u >> 16) & 1u);
  return (unsigned short)(u >> 16);
}
// fp16 bit helpers
__device__ __forceinline__ float h2f_bits(unsigned short us) {
  __half_raw r; r.x = us; return __half2float(__half(r));
}
__device__ __forceinline__ unsigned short f2h_bits(float f) {
  return __half_as_ushort(__float2half(f));
}

// ---- agent-scope (cross-XCD) relaxed LOADS: sc1 ops bypass the
// non-coherent per-XCD L2s and read the device coherence point (MALL).
// Exchange protocol (v5): producers use PLAIN cached stores (L2 write-
// combining); the block leader's RELEASE-agent fence at the barrier emits
// buffer_wbl2 (writeback, NO invalidate) making them MALL-visible; consumers
// sc1-load. No plane written in-kernel is ever plain-read afterwards, so no
// stale-L2 hit path exists.
__device__ __forceinline__ unsigned int ld_dev_u32(const unsigned int* p) {
  return __hip_atomic_load(const_cast<unsigned int*>(p), __ATOMIC_RELAXED,
                           __HIP_MEMORY_SCOPE_AGENT);
}
__device__ __forceinline__ void st_dev_u32(unsigned int* p, unsigned int v) {
  __hip_atomic_store(p, v, __ATOMIC_RELAXED, __HIP_MEMORY_SCOPE_AGENT);
}
__device__ __forceinline__ unsigned long long ld_dev_u64(
    const unsigned long long* p) {
  return __hip_atomic_load(const_cast<unsigned long long*>(p),
                           __ATOMIC_RELAXED, __HIP_MEMORY_SCOPE_AGENT);
}

// trellis: fb(s,u)=u^s1^s0, nxt(s,u)=(fb<<2)|(s>>1), par(s,u)=u^s1^s2
__device__ __forceinline__ void gam_lin(float gxv, float gyv, float g[4]) {
  float es = EXP2F(-fabsf(gxv));
  float ep = EXP2F(-fabsf(gyv));
  float fu0 = gxv >= 0.0f ? 1.0f : es;
  float fu1 = gxv >= 0.0f ? es : 1.0f;
  float fp0 = gyv >= 0.0f ? 1.0f : ep;
  float fp1 = gyv >= 0.0f ? ep : 1.0f;
  g[0] = fu0 * fp0; g[1] = fu0 * fp1;
  g[2] = fu1 * fp0; g[3] = fu1 * fp1;
}

__device__ __forceinline__ void step_fwd_lin(float a[8], const float g[4]) {
  float an[8];
#pragma unroll
  for (int sn = 0; sn < 8; ++sn) {
    const int u0 = ((sn >> 2) ^ (sn & 1)) & 1;
    const int p0 = ((sn >> 2) ^ ((sn >> 1) & 1)) & 1;
    an[sn] = a[(sn & 3) * 2] * g[u0 * 2 + p0]
           + a[(sn & 3) * 2 + 1] * g[(u0 ^ 1) * 2 + (p0 ^ 1)];
  }
#pragma unroll
  for (int s = 0; s < 8; ++s) a[s] = an[s];
}

__device__ __forceinline__ void step_bwd_lin(float bt[8], const float g[4]) {
  float bn[8];
#pragma unroll
  for (int s = 0; s < 8; ++s) {
    const int s0 = s & 1, s1b = (s >> 1) & 1, s2b = (s >> 2) & 1;
    const int f0 = s1b ^ s0, q = s1b ^ s2b;
    bn[s] = g[q] * bt[(f0 << 2) | (s >> 1)]
          + g[2 + (q ^ 1)] * bt[((f0 ^ 1) << 2) | (s >> 1)];
  }
#pragma unroll
  for (int s = 0; s < 8; ++s) bt[s] = bn[s];
}

// max-renorm with tiny floor injection: NaN/underflow-proof
__device__ __forceinline__ void renorm_lin(float a[8]) {
  float m = fmaxf(fmaxf(fmaxf(a[0], a[1]), fmaxf(a[2], a[3])),
                  fmaxf(fmaxf(a[4], a[5]), fmaxf(a[6], a[7])));
  float r = RCPF(fmaxf(m, 1e-30f));
#pragma unroll
  for (int s = 0; s < 8; ++s) a[s] = fmaf(a[s], r, 1e-32f);
}

// ---- log8-packed boundary states: u8 = round(-16*log2(x)), clamp 255. ----
__device__ __forceinline__ unsigned long long pack8_log8(const float a[8]) {
  unsigned int us[8];
#pragma unroll
  for (int s = 0; s < 8; ++s) {
    float l = -16.0f * LOG2F(a[s]);
    l = fminf(l, 255.0f);
    us[s] = (unsigned int)(l + 0.5f);
  }
  unsigned int x = us[0] | (us[1] << 8) | (us[2] << 16) | (us[3] << 24);
  unsigned int y = us[4] | (us[5] << 8) | (us[6] << 16) | (us[7] << 24);
  return ((unsigned long long)y << 32) | x;
}

__device__ __forceinline__ void unpack8_log8(unsigned long long v, float a[8]) {
  unsigned int vx = (unsigned int)v, vy = (unsigned int)(v >> 32);
#pragma unroll
  for (int s = 0; s < 4; ++s)
    a[s] = EXP2F(-0.0625f * (float)((vx >> (8 * s)) & 0xFFu));
#pragma unroll
  for (int s = 0; s < 4; ++s)
    a[4 + s] = EXP2F(-0.0625f * (float)((vy >> (8 * s)) & 0xFFu));
}

// ---------------- tree barrier geometry -----------------------------------
// Per slot: 32 group-counter lines + 32 release lines + 1 root line, each
// 128 B. Arrive: leader does release-agent fence (buffer_wbl2: publishes its
// block's plain stores to MALL, no invalidate), then RMWs its group line;
// group-finisher RMWs root; root-finisher stores the 32 release flags.
// Pollers only read release lines. No line carries both RMW and poll traffic.
constexpr int NSLOT = 2 * NITER - 1;       // 11 barriers
constexpr int SLOT_U = 65 * 32;            // uints per slot
constexpr int BARS_U = 24576;              // alloc (>= NSLOT*SLOT_U = 22880)

__device__ __forceinline__ void tree_barrier(unsigned int* slotBase,
                                             unsigned int gsz) {
  __syncthreads();                         // all waves' stores are in L2
  if (threadIdx.x == 0) {
    // writeback dirty L2 (this XCD) -> MALL; emits NO buffer_inv.
    __builtin_amdgcn_fence(__ATOMIC_RELEASE, "agent");
    const unsigned int g = blockIdx.x & 31u;
    unsigned int* cnt = slotBase + g * 32;
    unsigned int* rel = slotBase + (32 + g) * 32;
    unsigned int* root = slotBase + 64 * 32;
    unsigned int m = __hip_atomic_fetch_add(cnt, 1u, __ATOMIC_RELAXED,
                                            __HIP_MEMORY_SCOPE_AGENT);
    if (m == gsz - 1u) {                   // last of group -> root
      unsigned int r = __hip_atomic_fetch_add(root, 1u, __ATOMIC_RELAXED,
                                              __HIP_MEMORY_SCOPE_AGENT);
      if (r == 31u) {                      // last group -> broadcast release
#pragma unroll
        for (int gg = 0; gg < 32; ++gg)
          st_dev_u32(slotBase + (32 + gg) * 32, 1u);
      }
    }
    while (!ld_dev_u32(rel))
      __builtin_amdgcn_s_sleep(2);
  }
  __syncthreads();
}

// ---------------- workspace layout (shared host/device) -------------------
struct WSL {
  float* lpostT;
  __half* gx1; __half* gx2;            // fp16 extrinsic planes, PAIR-PACKED:
                                       // u32 at [j*(B/2)+(b>>1)] = cols b,b+1
  unsigned short* gy1; unsigned short* gy2;
  __half* ls1; __half* ls2;
  int* inv;
  unsigned int* bars;
  unsigned long long *S1a, *S1b, *T1a, *T1b, *S2a, *S2b, *T2a, *T2b;
};

__host__ __device__ inline WSL ws_layout(char* ws) {
  const size_t KB = (size_t)K_ * B_;
  WSL w; char* p = ws;
  w.lpostT = (float*)p;            p += KB * 4;
  w.gx1    = (__half*)p;           p += KB * 2;
  w.gx2    = (__half*)p;           p += KB * 2;
  w.gy1    = (unsigned short*)p;   p += KB * 2;
  w.gy2    = (unsigned short*)p;   p += KB * 2;
  w.ls1    = (__half*)p;           p += KB * 2;
  w.ls2    = (__half*)p;           p += KB * 2;
  w.inv    = (int*)p;              p += (size_t)K_ * 4;
  w.bars   = (unsigned int*)p;     p += (size_t)BARS_U * 4;
  const size_t SB = (size_t)(C_ + 1) * B_;          // ull elements
  w.S1a = (unsigned long long*)p;  p += SB * 8;
  w.S1b = (unsigned long long*)p;  p += SB * 8;
  w.T1a = (unsigned long long*)p;  p += SB * 8;
  w.T1b = (unsigned long long*)p;  p += SB * 8;
  w.S2a = (unsigned long long*)p;  p += SB * 8;
  w.S2b = (unsigned long long*)p;  p += SB * 8;
  w.T2a = (unsigned long long*)p;  p += SB * 8;
  w.T2b = (unsigned long long*)p;  p += SB * 8;
  return w;                                          // ~42.2 MB total
}

// ---------------- one windowed BCJR half-iteration (linear domain) --------
// DEV=true: persistent-kernel phase. Exchanged-plane LOADS use agent (sc1)
// ops unless gxc (gx plane produced by a prior dispatch -> plain cached);
// all STORES are plain cached (published by the barrier's release fence).
// DEV=false: plain-launch fallback. Numerics bit-identical to the proven
// baseline (extrinsic rounded through fp16).
template <bool DEV>
__device__ __forceinline__ void half_body(
    const int c,
    const __half* __restrict__ gx,
    const unsigned short* __restrict__ gy,
    const __half* __restrict__ lsloc,
    const int* __restrict__ map,
    __half* __restrict__ gxother,
    float* __restrict__ lpost_out,
    const unsigned long long* __restrict__ Sread,
    unsigned long long* __restrict__ Swrite,
    const unsigned long long* __restrict__ Tread,
    unsigned long long* __restrict__ Twrite,
    int wmode, int mode, int wrS, bool gxc) {
  const int b = threadIdx.x;
  const int kv = c * L_;
  const int kend = kv + L_;
  const unsigned int* gxp = (const unsigned int*)gx;   // packed [K][B/2]
  const int bh = b >> 1;
  const unsigned int hsel = (b & 1) * 16;              // shift for my half
  const bool gdev = DEV && !gxc;

  // ---- issue ALL independent loads upfront ----
  float gvx[L_];
  unsigned short rgy[L_];
  __half hls[L_];
#pragma unroll
  for (int i = 0; i < L_; ++i) {
    size_t o2 = (size_t)(kv + i) * (B_ / 2) + bh;
    unsigned int u = gdev ? ld_dev_u32(gxp + o2) : gxp[o2];
    gvx[i] = h2f_bits((unsigned short)(u >> hsel));
    rgy[i] = gy[(size_t)(kv + i) * B_ + b];
  }
  if (mode == 0) {
#pragma unroll
    for (int i = 0; i < L_; ++i)
      hls[i] = lsloc[(size_t)(kv + i) * B_ + b];   // local rows, cached
  }
  int jmap[L_];
#pragma unroll
  for (int i = 0; i < L_; ++i) jmap[i] = map[kv + i];     // block-uniform
  unsigned long long sraw = 0, traw = 0;
  float wfx[W0_], wbx[W0_];
  unsigned short wfy[W0_], wby[W0_];
  if (wmode == 2) {
    if (c > 0) {
      const size_t o = (size_t)c * B_ + b;
      sraw = DEV ? ld_dev_u64(Sread + o) : Sread[o];
    }
    if (c < C_ - 1) {
      const size_t o = (size_t)(c + 1) * B_ + b;
      traw = DEV ? ld_dev_u64(Tread + o) : Tread[o];
    }
  } else {
    // warmup gammas, all upfront (wu == W0_ exactly, since kv >= W0_ at c>=1)
    if (c > 0) {
#pragma unroll
      for (int q = 0; q < W0_; ++q) {
        size_t o2 = (size_t)(kv - W0_ + q) * (B_ / 2) + bh;
        unsigned int u = gdev ? ld_dev_u32(gxp + o2) : gxp[o2];
        wfx[q] = h2f_bits((unsigned short)(u >> hsel));
        wfy[q] = gy[(size_t)(kv - W0_ + q) * B_ + b];
      }
    }
    if (c < C_ - 1) {
#pragma unroll
      for (int q = 0; q < W0_; ++q) {
        size_t o2 = (size_t)(kend + W0_ - 1 - q) * (B_ / 2) + bh;
        unsigned int u = gdev ? ld_dev_u32(gxp + o2) : gxp[o2];
        wbx[q] = h2f_bits((unsigned short)(u >> hsel));
        wby[q] = gy[(size_t)(kend + W0_ - 1 - q) * B_ + b];
      }
    }
  }

  // ---- valid gammas (gvx kept: needed for extrinsic) ----
  float gc[L_][4];
#pragma unroll
  for (int i = 0; i < L_; ++i) gam_lin(gvx[i], b2f(rgy[i]), gc[i]);

  // ---------------- forward ----------------
  float a[8];
  if (c == 0) {
    a[0] = 1.0f;
#pragma unroll
    for (int s = 1; s < 8; ++s) a[s] = 0.0f;
  } else if (wmode == 0) {
    if (c == 1) {                    // warmup starts at position 0: exact init
      a[0] = 1.0f;
#pragma unroll
      for (int s = 1; s < 8; ++s) a[s] = 0.0f;
    } else {
#pragma unroll
      for (int s = 0; s < 8; ++s) a[s] = 1.0f;
    }
#pragma unroll
    for (int q = 0; q < W0_; ++q) {
      float g[4];
      gam_lin(wfx[q], b2f(wfy[q]), g);
      step_fwd_lin(a, g);
      if (q & 1) renorm_lin(a);
    }
  } else {
    unpack8_log8(sraw, a);           // pure inheritance (c>0 here)
  }
  // valid region: record alpha, then step (all L steps -> a = alpha(kend))
  float a2d[L_][8];
#pragma unroll
  for (int i = 0; i < L_; ++i) {
#pragma unroll
    for (int s = 0; s < 8; ++s) a2d[i][s] = a[s];
    step_fwd_lin(a, gc[i]);
    if (i & 1) renorm_lin(a);
  }
  if (wrS)
    Swrite[(size_t)(c + 1) * B_ + b] = pack8_log8(a);   // plain cached store

  // ---------------- backward + posterior ----------------
  float bt[8];
  if (c == C_ - 1) {
#pragma unroll
    for (int s = 0; s < 8; ++s) bt[s] = 1.0f;    // exact tail init (uniform)
  } else if (wmode == 0) {
#pragma unroll
    for (int s = 0; s < 8; ++s) bt[s] = 1.0f;    // uniform (exact at c=C_-2)
#pragma unroll
    for (int q = 0; q < W0_; ++q) {
      float g[4];
      gam_lin(wbx[q], b2f(wby[q]), g);
      step_bwd_lin(bt, g);
      if (q & 1) renorm_lin(bt);
    }
  } else {
    unpack8_log8(traw, bt);          // pure inheritance (c<C_-1 here)
  }
  // valid region, descending: posterior + extrinsic + beta step
#pragma unroll
  for (int ii = 0; ii < L_; ++ii) {
    const int i = L_ - 1 - ii;
    const float* g = gc[i];
    float s00 = 0.0f, s01 = 0.0f, s10 = 0.0f, s11 = 0.0f;
    float bn[8];
#pragma unroll
    for (int s = 0; s < 8; ++s) {
      const int s0 = s & 1, s1b = (s >> 1) & 1, s2b = (s >> 2) & 1;
      const int f0 = s1b ^ s0, q = s1b ^ s2b;
      float b0 = bt[(f0 << 2) | (s >> 1)];
      float b1 = bt[((f0 ^ 1) << 2) | (s >> 1)];
      float m0 = a2d[i][s] * b0;
      float m1 = a2d[i][s] * b1;
      if (q == 0) { s00 += m0; s10 += m1; } else { s01 += m0; s11 += m1; }
      bn[s] = g[q] * b0 + g[2 + (q ^ 1)] * b1;
    }
    float t0 = g[0] * s00 + g[1] * s01;
    float t1 = g[3] * s10 + g[2] * s11;
    float lpost = LOG2F(fmaxf(t0, 1e-37f)) - LOG2F(fmaxf(t1, 1e-37f));
    if (mode == 0) {
      float le = lpost - gvx[i];                 // lpost - (ls + la)
      unsigned short us = f2h_bits(__half2float(hls[i]) + le);
      // pair-pack with lane partner (jmap row is uniform across lanes)
      unsigned int po = (unsigned int)__shfl_xor((int)us, 1);
      if (!(b & 1)) {
        unsigned int u = (unsigned int)us | (po << 16);
        ((unsigned int*)gxother)[(size_t)jmap[i] * (B_ / 2) + bh] = u;
      }
    } else {
      lpost_out[(size_t)jmap[i] * B_ + b] = -LN2 * lpost;  // final value
    }
#pragma unroll
    for (int s = 0; s < 8; ++s) bt[s] = bn[s];
    if (ii & 1) renorm_lin(bt);
  }
  if (wrS)
    Twrite[(size_t)c * B_ + b] = pack8_log8(bt);        // plain cached store
}

// ---------------- persistent megakernel (plain launch) --------------------
// No grid.sync anywhere -> no cooperative API needed. Host guarantees
// co-residency (grid <= occupancy x CUs, 8 blocks/CU capacity at 64 VGPR).
__global__ __launch_bounds__(256, 4) void k_fused(const int* __restrict__ perm,
                                                  char* __restrict__ ws) {
  WSL w = ws_layout(ws);
  const int tid = threadIdx.x;
  const unsigned int gsz = gridDim.x >> 5;   // blocks per barrier group

  // prologue: ls2 gather. Rows c*L..c*L+5 are written and later read by the
  // SAME block (grid-stride mapping identical in every phase) -> plain
  // cached stores, no barrier needed.
  for (int c = blockIdx.x; c < C_; c += gridDim.x) {
#pragma unroll
    for (int r = 0; r < L_; ++r) {
      const int j = c * L_ + r;
      w.ls2[(size_t)j * B_ + tid] = w.ls1[(size_t)perm[j] * B_ + tid];
    }
  }

  int slot = 0;
  for (int it = 0; it < NITER; ++it) {
    const int pr = it & 1;
    const int wm = (it == 0) ? 0 : 2;
    const int wrS = (it != NITER - 1) ? 1 : 0;
    unsigned long long* S1r = pr ? w.S1b : w.S1a;
    unsigned long long* S1w = pr ? w.S1a : w.S1b;
    unsigned long long* T1r = pr ? w.T1b : w.T1a;
    unsigned long long* T1w = pr ? w.T1a : w.T1b;
    unsigned long long* S2r = pr ? w.S2b : w.S2a;
    unsigned long long* S2w = pr ? w.S2a : w.S2b;
    unsigned long long* T2r = pr ? w.T2b : w.T2a;
    unsigned long long* T2w = pr ? w.T2a : w.T2b;
    // phase 0 (decoder 1): extrinsic -> gx2[inv[kk]]; local ls plane = ls1.
    // gx1 holds prep1's packed fp16 ls values at it0 (la=0) -> cached reads.
    for (int c = blockIdx.x; c < C_; c += gridDim.x)
      half_body<true>(c, w.gx1, w.gy1, w.ls1, w.inv, w.gx2, w.lpostT,
                      S1r, S1w, T1r, T1w, wm, 0, wrS, it == 0);
    tree_barrier(w.bars + slot * SLOT_U, gsz); ++slot;
    // phase 1 (decoder 2): extrinsic -> gx1[perm[kk]]; local ls plane = ls2
    for (int c = blockIdx.x; c < C_; c += gridDim.x)
      half_body<true>(c, w.gx2, w.gy2, w.ls2, perm, w.gx1, w.lpostT,
                      S2r, S2w, T2r, T2w, wm, (it == NITER - 1) ? 1 : 0, wrS,
                      false);
    if (it != NITER - 1) { tree_barrier(w.bars + slot * SLOT_U, gsz); ++slot; }
  }
  // lpostT written with plain stores; kernel-end implicit release publishes
  // it for the separate k_out dispatch.
}

// ---------------- fallback kernels (proven multi-launch path) -------------
__global__ __launch_bounds__(256, 4) void k_half(
    const __half* __restrict__ gx, const unsigned short* __restrict__ gy,
    const __half* __restrict__ lsloc, const int* __restrict__ map,
    __half* __restrict__ gxother, float* __restrict__ lpost_out,
    const unsigned long long* __restrict__ Sread,
    unsigned long long* __restrict__ Swrite,
    const unsigned long long* __restrict__ Tread,
    unsigned long long* __restrict__ Twrite,
    int wmode, int mode, int wrS) {
  half_body<false>(blockIdx.x, gx, gy, lsloc, map, gxother, lpost_out,
                   Sread, Swrite, Tread, Twrite, wmode, mode, wrS, true);
}

__global__ __launch_bounds__(256) void k_prep2(const __half* __restrict__ ls1,
                                               const int* __restrict__ perm,
                                               __half* __restrict__ ls2) {
  const int b = threadIdx.x;
#pragma unroll
  for (int r = 0; r < 8; ++r) {
    const int j = blockIdx.x * 8 + r;
    ls2[(size_t)j * B_ + b] = ls1[(size_t)perm[j] * B_ + b];
  }
}

__global__ __launch_bounds__(256) void k_out(const float* __restrict__ lpostT,
                                             float* __restrict__ out) {
  __shared__ float t[64][65];
  const int tid = threadIdx.x;
  const int i0 = blockIdx.x * 64, b0 = blockIdx.y * 64;
  const int tb = tid & 63, iq = tid >> 6;
  for (int ii = iq; ii < 64; ii += 4) {
    t[ii][tb] = lpostT[(size_t)(i0 + ii) * B_ + (b0 + tb)];
  }
  __syncthreads();
  const int ik = tid & 63, bq = tid >> 6;
  for (int bb = bq; bb < 64; bb += 4) {
    out[(size_t)(b0 + bb) * K_ + (i0 + ik)] = t[ik][bb];
  }
}

// ---------------- prep: de-interleave + transpose + scale to log2 domain --
// Also: writes pair-packed fp16 ls into gx1 (it0 phase-0 gamma plane, la=0),
// computes inv, and zeroes the barrier region (kernel-end flush publishes
// everything for the persistent kernel).
__global__ __launch_bounds__(256) void k_prep1(const float* __restrict__ inp,
                                               const int* __restrict__ perm,
                                               __half* __restrict__ gx1,
                                               __half* __restrict__ ls1,
                                               unsigned short* __restrict__ gy1,
                                               unsigned short* __restrict__ gy2,
                                               int* __restrict__ inv,
                                               unsigned int* __restrict__ bars) {
  __shared__ float t[3][64][65];
  const int tid = threadIdx.x;
  const int k0 = blockIdx.x * 64, b0 = blockIdx.y * 64;
  const int tk = tid & 63, tq = tid >> 6;
  for (int bb = tq; bb < 64; bb += 4) {
    size_t base = (size_t)(b0 + bb) * (3 * K_) + 3 * (size_t)(k0 + tk);
    t[0][bb][tk] = inp[base + 0];
    t[1][bb][tk] = inp[base + 1];
    t[2][bb][tk] = inp[base + 2];
  }
  __syncthreads();
  const int tb = tid & 63, kq = tid >> 6;
  for (int kk = kq; kk < 64; kk += 4) {
    size_t o = (size_t)(k0 + kk) * B_ + (b0 + tb);
    float sv = -LOG2E * t[0][tb][kk];
    float p1 = -LOG2E * t[1][tb][kk];
    float p2 = -LOG2E * t[2][tb][kk];
    ls1[o] = __float2half(sv);
    gy1[o] = f2b(p1);
    gy2[o] = f2b(p2);
    if (!(tb & 1)) {                      // pair-packed gx1 (cols tb, tb+1)
      float sv1 = -LOG2E * t[0][tb + 1][kk];
      unsigned int u = (unsigned int)f2h_bits(sv) |
                       ((unsigned int)f2h_bits(sv1) << 16);
      ((unsigned int*)gx1)[o >> 1] = u;
    }
  }
  if (blockIdx.y == 0 && tid < 64) {
    const int j = k0 + tid;
    inv[perm[j]] = j;
  }
  if (blockIdx.y == 1 && blockIdx.x < BARS_U / 1024) {   // zero barrier region
#pragma unroll
    for (int r = 0; r < 4; ++r)
      bars[(size_t)blockIdx.x * 1024 + r * 256 + tid] = 0;
  }
}

// ---------------- launch ---------------------------------------------------
static void launch_fallback(const int* perm, float* out, char* wsb,
                            hipStream_t stream) {
  WSL w = ws_layout(wsb);
  k_prep2<<<K_ / 8, 256, 0, stream>>>(w.ls1, perm, w.ls2);
  for (int it = 0; it < NITER; ++it) {
    const int pr = it & 1;
    const int wm = (it == 0) ? 0 : 2;
    const int wrS = (it != NITER - 1) ? 1 : 0;
    unsigned long long* S1r = pr ? w.S1b : w.S1a;
    unsigned long long* S1w = pr ? w.S1a : w.S1b;
    unsigned long long* T1r = pr ? w.T1b : w.T1a;
    unsigned long long* T1w = pr ? w.T1a : w.T1b;
    unsigned long long* S2r = pr ? w.S2b : w.S2a;
    unsigned long long* S2w = pr ? w.S2a : w.S2b;
    unsigned long long* T2r = pr ? w.T2b : w.T2a;
    unsigned long long* T2w = pr ? w.T2a : w.T2b;
    k_half<<<C_, 256, 0, stream>>>(w.gx1, w.gy1, w.ls1, w.inv, w.gx2,
                                   w.lpostT, S1r, S1w, T1r, T1w, wm, 0, wrS);
    k_half<<<C_, 256, 0, stream>>>(w.gx2, w.gy2, w.ls2, perm, w.gx1,
                                   w.lpostT, S2r, S2w, T2r, T2w, wm,
                                   (it == NITER - 1) ? 1 : 0, wrS);
  }
  k_out<<<dim3(K_ / 64, B_ / 64), 256, 0, stream>>>(w.lpostT, out);
}

extern "C" void kernel_launch(void* const* d_in, const int* in_sizes, int n_in,
                              void* d_out, int out_size, void* d_ws, size_t ws_size,
                              hipStream_t stream) {
  (void)in_sizes; (void)n_in; (void)out_size; (void)ws_size;
  const float* inp = (const float*)d_in[0];
  const int* perm = (const int*)d_in[1];
  float* out = (float*)d_out;
  char* wsb = (char*)d_ws;
  WSL w = ws_layout(wsb);

  k_prep1<<<dim3(K_ / 64, B_ / 64), 256, 0, stream>>>(
      inp, perm, w.gx1, w.ls1, w.gy1, w.gy2, w.inv, w.bars);

  // mode: 0 = undecided, 1 = persistent plain-launch, 2 = fallback.
  // The persistent kernel needs all blocks co-resident: guaranteed by
  // grid <= maxActiveBlocksPerCU x CUs (64 VGPR / no LDS -> 8 blocks/CU,
  // so grid=1024 uses half of capacity). No cooperative API involved.
  static int g_mode = 0;
  static int g_grid = 0;

  if (g_mode == 0) {
    int nb = 0;
    if (hipOccupancyMaxActiveBlocksPerMultiprocessor(&nb, k_fused, 256, 0)
            != hipSuccess)
      nb = 0;
    int ncu = 0;
    hipDeviceProp_t prop;
    int dev = 0;
    (void)hipGetDevice(&dev);
    if (hipGetDeviceProperties(&prop, dev) == hipSuccess)
      ncu = prop.multiProcessorCount;
    long long g = (long long)nb * (long long)ncu;
    int grid = (g > C_) ? C_ : (int)g;
    grid &= ~31;                          // tree barrier needs grid % 32 == 0
    if (grid >= 32) { g_mode = 1; g_grid = grid; }
    else            { g_mode = 2; }
  }

  if (g_mode == 1) {
    k_fused<<<g_grid, 256, 0, stream>>>(perm, wsb);
    k_out<<<dim3(K_ / 64, B_ / 64), 256, 0, stream>>>(w.lpostT, out);
  } else {
    launch_fallback(perm, out, wsb, stream);
  }
}

// Round 6
// 243.666 us; speedup vs baseline: 1.4209x; 1.4209x over previous
//
#include <hip/hip_runtime.h>
#include <hip/hip_fp16.h>

// ---------------- problem constants ----------------
constexpr int B_ = 256;        // batch
constexpr int K_ = 6144;       // block length
constexpr int NITER = 6;
constexpr int L_ = 6;          // window valid length -> C_=1024 chunks
constexpr int W0_ = 6;         // uniform-init warmup (iteration 0)
constexpr int C_ = K_ / L_;    // chunks = 1024
constexpr float LOG2E = 1.4426950408889634f;
constexpr float LN2   = 0.6931471805599453f;

static_assert(K_ % L_ == 0, "");
static_assert((L_ % 2) == 0 && (W0_ % 2) == 0, "");
static_assert(W0_ <= L_, "uniform-warmup trick requires W0 <= L");

#if __has_builtin(__builtin_amdgcn_exp2f)
#define EXP2F(x) __builtin_amdgcn_exp2f(x)
#else
#define EXP2F(x) exp2f(x)
#endif
#if __has_builtin(__builtin_amdgcn_logf)
#define LOG2F(x) __builtin_amdgcn_logf(x)
#else
#define LOG2F(x) log2f(x)
#endif
#if __has_builtin(__builtin_amdgcn_rcpf)
#define RCPF(x) __builtin_amdgcn_rcpf(x)
#else
#define RCPF(x) (1.0f / (x))
#endif

// ---- bf16 scalar helpers (RNE) ----
__device__ __forceinline__ float b2f(unsigned short u) {
  return __uint_as_float((unsigned)u << 16);
}
__device__ __forceinline__ unsigned short f2b(float f) {
  unsigned u = __float_as_uint(f);
  u += 0x7FFFu + ((u >> 16) & 1u);
  return (unsigned short)(u >> 16);
}
// fp16 bit helpers
__device__ __forceinline__ float h2f_bits(unsigned short us) {
  __half_raw r; r.x = us; return __half2float(__half(r));
}
__device__ __forceinline__ unsigned short f2h_bits(float f) {
  return __half_as_ushort(__float2half(f));
}

// ---- agent-scope (cross-XCD) relaxed accessors: sc1 ops bypass the
// non-coherent per-XCD L2s and hit the device coherence point (MALL).
// Exchange protocol (round-4, proven 149us): producers sc1 write-through
// store; each wave drains vmcnt at __syncthreads before the barrier arrive;
// consumers sc1-load. NO buffer_wbl2 / buffer_inv anywhere, so read-only
// planes (gy/ls/inv/perm) stay L2-resident across all 12 phases. (Round-5's
// per-leader release-fence wbl2 regressed 149->376us: 11x1024 serialized
// L2-writeback scans.)
__device__ __forceinline__ unsigned int ld_dev_u32(const unsigned int* p) {
  return __hip_atomic_load(const_cast<unsigned int*>(p), __ATOMIC_RELAXED,
                           __HIP_MEMORY_SCOPE_AGENT);
}
__device__ __forceinline__ void st_dev_u32(unsigned int* p, unsigned int v) {
  __hip_atomic_store(p, v, __ATOMIC_RELAXED, __HIP_MEMORY_SCOPE_AGENT);
}
__device__ __forceinline__ unsigned long long ld_dev_u64(
    const unsigned long long* p) {
  return __hip_atomic_load(const_cast<unsigned long long*>(p),
                           __ATOMIC_RELAXED, __HIP_MEMORY_SCOPE_AGENT);
}
__device__ __forceinline__ void st_dev_u64(unsigned long long* p,
                                           unsigned long long v) {
  __hip_atomic_store(p, v, __ATOMIC_RELAXED, __HIP_MEMORY_SCOPE_AGENT);
}

// trellis: fb(s,u)=u^s1^s0, nxt(s,u)=(fb<<2)|(s>>1), par(s,u)=u^s1^s2
__device__ __forceinline__ void gam_lin(float gxv, float gyv, float g[4]) {
  float es = EXP2F(-fabsf(gxv));
  float ep = EXP2F(-fabsf(gyv));
  float fu0 = gxv >= 0.0f ? 1.0f : es;
  float fu1 = gxv >= 0.0f ? es : 1.0f;
  float fp0 = gyv >= 0.0f ? 1.0f : ep;
  float fp1 = gyv >= 0.0f ? ep : 1.0f;
  g[0] = fu0 * fp0; g[1] = fu0 * fp1;
  g[2] = fu1 * fp0; g[3] = fu1 * fp1;
}

__device__ __forceinline__ void step_fwd_lin(float a[8], const float g[4]) {
  float an[8];
#pragma unroll
  for (int sn = 0; sn < 8; ++sn) {
    const int u0 = ((sn >> 2) ^ (sn & 1)) & 1;
    const int p0 = ((sn >> 2) ^ ((sn >> 1) & 1)) & 1;
    an[sn] = a[(sn & 3) * 2] * g[u0 * 2 + p0]
           + a[(sn & 3) * 2 + 1] * g[(u0 ^ 1) * 2 + (p0 ^ 1)];
  }
#pragma unroll
  for (int s = 0; s < 8; ++s) a[s] = an[s];
}

__device__ __forceinline__ void step_bwd_lin(float bt[8], const float g[4]) {
  float bn[8];
#pragma unroll
  for (int s = 0; s < 8; ++s) {
    const int s0 = s & 1, s1b = (s >> 1) & 1, s2b = (s >> 2) & 1;
    const int f0 = s1b ^ s0, q = s1b ^ s2b;
    bn[s] = g[q] * bt[(f0 << 2) | (s >> 1)]
          + g[2 + (q ^ 1)] * bt[((f0 ^ 1) << 2) | (s >> 1)];
  }
#pragma unroll
  for (int s = 0; s < 8; ++s) bt[s] = bn[s];
}

// max-renorm with tiny floor injection: NaN/underflow-proof
__device__ __forceinline__ void renorm_lin(float a[8]) {
  float m = fmaxf(fmaxf(fmaxf(a[0], a[1]), fmaxf(a[2], a[3])),
                  fmaxf(fmaxf(a[4], a[5]), fmaxf(a[6], a[7])));
  float r = RCPF(fmaxf(m, 1e-30f));
#pragma unroll
  for (int s = 0; s < 8; ++s) a[s] = fmaf(a[s], r, 1e-32f);
}

// ---- log8-packed boundary states: u8 = round(-16*log2(x)), clamp 255. ----
__device__ __forceinline__ unsigned long long pack8_log8(const float a[8]) {
  unsigned int us[8];
#pragma unroll
  for (int s = 0; s < 8; ++s) {
    float l = -16.0f * LOG2F(a[s]);
    l = fminf(l, 255.0f);
    us[s] = (unsigned int)(l + 0.5f);
  }
  unsigned int x = us[0] | (us[1] << 8) | (us[2] << 16) | (us[3] << 24);
  unsigned int y = us[4] | (us[5] << 8) | (us[6] << 16) | (us[7] << 24);
  return ((unsigned long long)y << 32) | x;
}

__device__ __forceinline__ void unpack8_log8(unsigned long long v, float a[8]) {
  unsigned int vx = (unsigned int)v, vy = (unsigned int)(v >> 32);
#pragma unroll
  for (int s = 0; s < 4; ++s)
    a[s] = EXP2F(-0.0625f * (float)((vx >> (8 * s)) & 0xFFu));
#pragma unroll
  for (int s = 0; s < 4; ++s)
    a[4 + s] = EXP2F(-0.0625f * (float)((vy >> (8 * s)) & 0xFFu));
}

// ---------------- tree barrier geometry -----------------------------------
// Per slot: 32 group-counter lines + 32 release lines + 1 root line, each
// 128 B. Arrive: leader RMWs its group line (max 32 serialized RMWs,
// parallel across lines); group-finisher RMWs root; root-finisher stores the
// 32 release flags. Pollers only read release lines. No line carries both
// RMW and poll traffic. (Proven at 149us/kernel in round 4.)
constexpr int NSLOT = 2 * NITER - 1;       // 11 barriers
constexpr int SLOT_U = 65 * 32;            // uints per slot
constexpr int BARS_U = 24576;              // alloc (>= NSLOT*SLOT_U = 22880)

__device__ __forceinline__ void tree_barrier(unsigned int* slotBase,
                                             unsigned int gsz) {
  __syncthreads();                         // each wave drains vmcnt here
  if (threadIdx.x == 0) {
    asm volatile("s_waitcnt vmcnt(0)" ::: "memory");
    const unsigned int g = blockIdx.x & 31u;
    unsigned int* cnt = slotBase + g * 32;
    unsigned int* rel = slotBase + (32 + g) * 32;
    unsigned int* root = slotBase + 64 * 32;
    unsigned int m = __hip_atomic_fetch_add(cnt, 1u, __ATOMIC_RELAXED,
                                            __HIP_MEMORY_SCOPE_AGENT);
    if (m == gsz - 1u) {                   // last of group -> root
      unsigned int r = __hip_atomic_fetch_add(root, 1u, __ATOMIC_RELAXED,
                                              __HIP_MEMORY_SCOPE_AGENT);
      if (r == 31u) {                      // last group -> broadcast release
#pragma unroll
        for (int gg = 0; gg < 32; ++gg)
          st_dev_u32(slotBase + (32 + gg) * 32, 1u);
      }
    }
    while (!ld_dev_u32(rel))
      __builtin_amdgcn_s_sleep(2);
  }
  __syncthreads();
}

// ---------------- workspace layout (shared host/device) -------------------
struct WSL {
  float* lpostT;
  __half* gx1; __half* gx2;            // fp16 extrinsic planes, PAIR-PACKED:
                                       // u32 at [j*(B/2)+(b>>1)] = cols b,b+1
  unsigned short* gy1; unsigned short* gy2;
  __half* ls1; __half* ls2;
  int* inv;
  unsigned int* bars;
  unsigned long long *S1a, *S1b, *T1a, *T1b, *S2a, *S2b, *T2a, *T2b;
};

__host__ __device__ inline WSL ws_layout(char* ws) {
  const size_t KB = (size_t)K_ * B_;
  WSL w; char* p = ws;
  w.lpostT = (float*)p;            p += KB * 4;
  w.gx1    = (__half*)p;           p += KB * 2;
  w.gx2    = (__half*)p;           p += KB * 2;
  w.gy1    = (unsigned short*)p;   p += KB * 2;
  w.gy2    = (unsigned short*)p;   p += KB * 2;
  w.ls1    = (__half*)p;           p += KB * 2;
  w.ls2    = (__half*)p;           p += KB * 2;
  w.inv    = (int*)p;              p += (size_t)K_ * 4;
  w.bars   = (unsigned int*)p;     p += (size_t)BARS_U * 4;
  const size_t SB = (size_t)(C_ + 1) * B_;          // ull elements
  w.S1a = (unsigned long long*)p;  p += SB * 8;
  w.S1b = (unsigned long long*)p;  p += SB * 8;
  w.T1a = (unsigned long long*)p;  p += SB * 8;
  w.T1b = (unsigned long long*)p;  p += SB * 8;
  w.S2a = (unsigned long long*)p;  p += SB * 8;
  w.S2b = (unsigned long long*)p;  p += SB * 8;
  w.T2a = (unsigned long long*)p;  p += SB * 8;
  w.T2b = (unsigned long long*)p;  p += SB * 8;
  return w;                                          // ~42.2 MB total
}

// ---------------- one windowed BCJR half-iteration (linear domain) --------
// DEV=true: persistent-kernel phase; exchanged planes (gx, gxother, S/T) use
// agent-scope sc1 ops, except gxc (gx produced by a prior dispatch -> plain
// cached reads). DEV=false: plain-launch fallback. Numerics bit-identical to
// the proven baseline (extrinsic rounded through fp16).
template <bool DEV>
__device__ __forceinline__ void half_body(
    const int c,
    const __half* __restrict__ gx,
    const unsigned short* __restrict__ gy,
    const __half* __restrict__ lsloc,
    const int* __restrict__ map,
    __half* __restrict__ gxother,
    float* __restrict__ lpost_out,
    const unsigned long long* __restrict__ Sread,
    unsigned long long* __restrict__ Swrite,
    const unsigned long long* __restrict__ Tread,
    unsigned long long* __restrict__ Twrite,
    int wmode, int mode, int wrS, bool gxc) {
  const int b = threadIdx.x;
  const int kv = c * L_;
  const int kend = kv + L_;
  const unsigned int* gxp = (const unsigned int*)gx;   // packed [K][B/2]
  const int bh = b >> 1;
  const unsigned int hsel = (b & 1) * 16;              // shift for my half
  const bool gdev = DEV && !gxc;

  // ---- issue ALL independent loads upfront ----
  float gvx[L_];
  unsigned short rgy[L_];
  __half hls[L_];
#pragma unroll
  for (int i = 0; i < L_; ++i) {
    size_t o2 = (size_t)(kv + i) * (B_ / 2) + bh;
    unsigned int u = gdev ? ld_dev_u32(gxp + o2) : gxp[o2];
    gvx[i] = h2f_bits((unsigned short)(u >> hsel));
    rgy[i] = gy[(size_t)(kv + i) * B_ + b];
  }
  if (mode == 0) {
#pragma unroll
    for (int i = 0; i < L_; ++i)
      hls[i] = lsloc[(size_t)(kv + i) * B_ + b];   // local rows, cached
  }
  int jmap[L_];
#pragma unroll
  for (int i = 0; i < L_; ++i) jmap[i] = map[kv + i];     // block-uniform
  unsigned long long sraw = 0, traw = 0;
  float wfx[W0_], wbx[W0_];
  unsigned short wfy[W0_], wby[W0_];
  if (wmode == 2) {
    if (c > 0) {
      const size_t o = (size_t)c * B_ + b;
      sraw = DEV ? ld_dev_u64(Sread + o) : Sread[o];
    }
    if (c < C_ - 1) {
      const size_t o = (size_t)(c + 1) * B_ + b;
      traw = DEV ? ld_dev_u64(Tread + o) : Tread[o];
    }
  } else {
    // warmup gammas, all upfront (wu == W0_ exactly, since kv >= W0_ at c>=1)
    if (c > 0) {
#pragma unroll
      for (int q = 0; q < W0_; ++q) {
        size_t o2 = (size_t)(kv - W0_ + q) * (B_ / 2) + bh;
        unsigned int u = gdev ? ld_dev_u32(gxp + o2) : gxp[o2];
        wfx[q] = h2f_bits((unsigned short)(u >> hsel));
        wfy[q] = gy[(size_t)(kv - W0_ + q) * B_ + b];
      }
    }
    if (c < C_ - 1) {
#pragma unroll
      for (int q = 0; q < W0_; ++q) {
        size_t o2 = (size_t)(kend + W0_ - 1 - q) * (B_ / 2) + bh;
        unsigned int u = gdev ? ld_dev_u32(gxp + o2) : gxp[o2];
        wbx[q] = h2f_bits((unsigned short)(u >> hsel));
        wby[q] = gy[(size_t)(kend + W0_ - 1 - q) * B_ + b];
      }
    }
  }

  // ---- valid gammas (gvx kept: needed for extrinsic) ----
  float gc[L_][4];
#pragma unroll
  for (int i = 0; i < L_; ++i) gam_lin(gvx[i], b2f(rgy[i]), gc[i]);

  // ---------------- forward ----------------
  float a[8];
  if (c == 0) {
    a[0] = 1.0f;
#pragma unroll
    for (int s = 1; s < 8; ++s) a[s] = 0.0f;
  } else if (wmode == 0) {
    if (c == 1) {                    // warmup starts at position 0: exact init
      a[0] = 1.0f;
#pragma unroll
      for (int s = 1; s < 8; ++s) a[s] = 0.0f;
    } else {
#pragma unroll
      for (int s = 0; s < 8; ++s) a[s] = 1.0f;
    }
#pragma unroll
    for (int q = 0; q < W0_; ++q) {
      float g[4];
      gam_lin(wfx[q], b2f(wfy[q]), g);
      step_fwd_lin(a, g);
      if (q & 1) renorm_lin(a);
    }
  } else {
    unpack8_log8(sraw, a);           // pure inheritance (c>0 here)
  }
  // valid region: record alpha, then step (all L steps -> a = alpha(kend))
  float a2d[L_][8];
#pragma unroll
  for (int i = 0; i < L_; ++i) {
#pragma unroll
    for (int s = 0; s < 8; ++s) a2d[i][s] = a[s];
    step_fwd_lin(a, gc[i]);
    if (i & 1) renorm_lin(a);
  }
  if (wrS) {
    unsigned long long v = pack8_log8(a);
    unsigned long long* p = Swrite + (size_t)(c + 1) * B_ + b;
    if (DEV) st_dev_u64(p, v); else *p = v;
  }

  // ---------------- backward + posterior ----------------
  float bt[8];
  if (c == C_ - 1) {
#pragma unroll
    for (int s = 0; s < 8; ++s) bt[s] = 1.0f;    // exact tail init (uniform)
  } else if (wmode == 0) {
#pragma unroll
    for (int s = 0; s < 8; ++s) bt[s] = 1.0f;    // uniform (exact at c=C_-2)
#pragma unroll
    for (int q = 0; q < W0_; ++q) {
      float g[4];
      gam_lin(wbx[q], b2f(wby[q]), g);
      step_bwd_lin(bt, g);
      if (q & 1) renorm_lin(bt);
    }
  } else {
    unpack8_log8(traw, bt);          // pure inheritance (c<C_-1 here)
  }
  // valid region, descending: posterior + extrinsic + beta step
#pragma unroll
  for (int ii = 0; ii < L_; ++ii) {
    const int i = L_ - 1 - ii;
    const float* g = gc[i];
    float s00 = 0.0f, s01 = 0.0f, s10 = 0.0f, s11 = 0.0f;
    float bn[8];
#pragma unroll
    for (int s = 0; s < 8; ++s) {
      const int s0 = s & 1, s1b = (s >> 1) & 1, s2b = (s >> 2) & 1;
      const int f0 = s1b ^ s0, q = s1b ^ s2b;
      float b0 = bt[(f0 << 2) | (s >> 1)];
      float b1 = bt[((f0 ^ 1) << 2) | (s >> 1)];
      float m0 = a2d[i][s] * b0;
      float m1 = a2d[i][s] * b1;
      if (q == 0) { s00 += m0; s10 += m1; } else { s01 += m0; s11 += m1; }
      bn[s] = g[q] * b0 + g[2 + (q ^ 1)] * b1;
    }
    float t0 = g[0] * s00 + g[1] * s01;
    float t1 = g[3] * s10 + g[2] * s11;
    float lpost = LOG2F(fmaxf(t0, 1e-37f)) - LOG2F(fmaxf(t1, 1e-37f));
    if (mode == 0) {
      float le = lpost - gvx[i];                 // lpost - (ls + la)
      unsigned short us = f2h_bits(__half2float(hls[i]) + le);
      // pair-pack with lane partner (jmap row is uniform across lanes)
      unsigned int po = (unsigned int)__shfl_xor((int)us, 1);
      if (!(b & 1)) {
        unsigned int u = (unsigned int)us | (po << 16);
        unsigned int* p =
            (unsigned int*)gxother + ((size_t)jmap[i] * (B_ / 2) + bh);
        if (DEV) st_dev_u32(p, u); else *p = u;
      }
    } else {
      lpost_out[(size_t)jmap[i] * B_ + b] = -LN2 * lpost;  // final value
    }
#pragma unroll
    for (int s = 0; s < 8; ++s) bt[s] = bn[s];
    if (ii & 1) renorm_lin(bt);
  }
  if (wrS) {
    unsigned long long v = pack8_log8(bt);
    unsigned long long* p = Twrite + (size_t)c * B_ + b;
    if (DEV) st_dev_u64(p, v); else *p = v;
  }
}

// ---------------- persistent megakernel (plain launch) --------------------
// No grid.sync anywhere -> no cooperative API needed. Host guarantees
// co-residency (grid <= occupancy x CUs; 64 VGPR / no LDS -> 8 blocks/CU
// capacity, grid=1024 uses half).
__global__ __launch_bounds__(256, 4) void k_fused(const int* __restrict__ perm,
                                                  char* __restrict__ ws) {
  WSL w = ws_layout(ws);
  const int tid = threadIdx.x;
  const unsigned int gsz = gridDim.x >> 5;   // blocks per barrier group

  // prologue: ls2 gather. Rows c*L..c*L+5 are written and later read by the
  // SAME block (grid-stride mapping identical in every phase) -> plain
  // cached stores, no barrier needed.
  for (int c = blockIdx.x; c < C_; c += gridDim.x) {
#pragma unroll
    for (int r = 0; r < L_; ++r) {
      const int j = c * L_ + r;
      w.ls2[(size_t)j * B_ + tid] = w.ls1[(size_t)perm[j] * B_ + tid];
    }
  }

  int slot = 0;
  for (int it = 0; it < NITER; ++it) {
    const int pr = it & 1;
    const int wm = (it == 0) ? 0 : 2;
    const int wrS = (it != NITER - 1) ? 1 : 0;
    unsigned long long* S1r = pr ? w.S1b : w.S1a;
    unsigned long long* S1w = pr ? w.S1a : w.S1b;
    unsigned long long* T1r = pr ? w.T1b : w.T1a;
    unsigned long long* T1w = pr ? w.T1a : w.T1b;
    unsigned long long* S2r = pr ? w.S2b : w.S2a;
    unsigned long long* S2w = pr ? w.S2a : w.S2b;
    unsigned long long* T2r = pr ? w.T2b : w.T2a;
    unsigned long long* T2w = pr ? w.T2a : w.T2b;
    // phase 0 (decoder 1): extrinsic -> gx2[inv[kk]]; local ls plane = ls1.
    // gx1 holds prep1's packed fp16 ls values at it0 (la=0) -> cached reads.
    for (int c = blockIdx.x; c < C_; c += gridDim.x)
      half_body<true>(c, w.gx1, w.gy1, w.ls1, w.inv, w.gx2, w.lpostT,
                      S1r, S1w, T1r, T1w, wm, 0, wrS, it == 0);
    tree_barrier(w.bars + slot * SLOT_U, gsz); ++slot;
    // phase 1 (decoder 2): extrinsic -> gx1[perm[kk]]; local ls plane = ls2
    for (int c = blockIdx.x; c < C_; c += gridDim.x)
      half_body<true>(c, w.gx2, w.gy2, w.ls2, perm, w.gx1, w.lpostT,
                      S2r, S2w, T2r, T2w, wm, (it == NITER - 1) ? 1 : 0, wrS,
                      false);
    if (it != NITER - 1) { tree_barrier(w.bars + slot * SLOT_U, gsz); ++slot; }
  }
  // lpostT written with plain stores; kernel-end implicit release publishes
  // it for the separate k_out dispatch.
}

// ---------------- fallback kernels (proven multi-launch path) -------------
__global__ __launch_bounds__(256, 4) void k_half(
    const __half* __restrict__ gx, const unsigned short* __restrict__ gy,
    const __half* __restrict__ lsloc, const int* __restrict__ map,
    __half* __restrict__ gxother, float* __restrict__ lpost_out,
    const unsigned long long* __restrict__ Sread,
    unsigned long long* __restrict__ Swrite,
    const unsigned long long* __restrict__ Tread,
    unsigned long long* __restrict__ Twrite,
    int wmode, int mode, int wrS) {
  half_body<false>(blockIdx.x, gx, gy, lsloc, map, gxother, lpost_out,
                   Sread, Swrite, Tread, Twrite, wmode, mode, wrS, true);
}

__global__ __launch_bounds__(256) void k_prep2(const __half* __restrict__ ls1,
                                               const int* __restrict__ perm,
                                               __half* __restrict__ ls2) {
  const int b = threadIdx.x;
#pragma unroll
  for (int r = 0; r < 8; ++r) {
    const int j = blockIdx.x * 8 + r;
    ls2[(size_t)j * B_ + b] = ls1[(size_t)perm[j] * B_ + b];
  }
}

__global__ __launch_bounds__(256) void k_out(const float* __restrict__ lpostT,
                                             float* __restrict__ out) {
  __shared__ float t[64][65];
  const int tid = threadIdx.x;
  const int i0 = blockIdx.x * 64, b0 = blockIdx.y * 64;
  const int tb = tid & 63, iq = tid >> 6;
  for (int ii = iq; ii < 64; ii += 4) {
    t[ii][tb] = lpostT[(size_t)(i0 + ii) * B_ + (b0 + tb)];
  }
  __syncthreads();
  const int ik = tid & 63, bq = tid >> 6;
  for (int bb = bq; bb < 64; bb += 4) {
    out[(size_t)(b0 + bb) * K_ + (i0 + ik)] = t[ik][bb];
  }
}

// ---------------- prep: de-interleave + transpose + scale to log2 domain --
// Also: writes pair-packed fp16 ls into gx1 (it0 phase-0 gamma plane, la=0),
// computes inv, and zeroes the barrier region (kernel-end flush publishes
// everything for the persistent kernel).
__global__ __launch_bounds__(256) void k_prep1(const float* __restrict__ inp,
                                               const int* __restrict__ perm,
                                               __half* __restrict__ gx1,
                                               __half* __restrict__ ls1,
                                               unsigned short* __restrict__ gy1,
                                               unsigned short* __restrict__ gy2,
                                               int* __restrict__ inv,
                                               unsigned int* __restrict__ bars) {
  __shared__ float t[3][64][65];
  const int tid = threadIdx.x;
  const int k0 = blockIdx.x * 64, b0 = blockIdx.y * 64;
  const int tk = tid & 63, tq = tid >> 6;
  for (int bb = tq; bb < 64; bb += 4) {
    size_t base = (size_t)(b0 + bb) * (3 * K_) + 3 * (size_t)(k0 + tk);
    t[0][bb][tk] = inp[base + 0];
    t[1][bb][tk] = inp[base + 1];
    t[2][bb][tk] = inp[base + 2];
  }
  __syncthreads();
  const int tb = tid & 63, kq = tid >> 6;
  for (int kk = kq; kk < 64; kk += 4) {
    size_t o = (size_t)(k0 + kk) * B_ + (b0 + tb);
    float sv = -LOG2E * t[0][tb][kk];
    float p1 = -LOG2E * t[1][tb][kk];
    float p2 = -LOG2E * t[2][tb][kk];
    ls1[o] = __float2half(sv);
    gy1[o] = f2b(p1);
    gy2[o] = f2b(p2);
    if (!(tb & 1)) {                      // pair-packed gx1 (cols tb, tb+1)
      float sv1 = -LOG2E * t[0][tb + 1][kk];
      unsigned int u = (unsigned int)f2h_bits(sv) |
                       ((unsigned int)f2h_bits(sv1) << 16);
      ((unsigned int*)gx1)[o >> 1] = u;
    }
  }
  if (blockIdx.y == 0 && tid < 64) {
    const int j = k0 + tid;
    inv[perm[j]] = j;
  }
  if (blockIdx.y == 1 && blockIdx.x < BARS_U / 1024) {   // zero barrier region
#pragma unroll
    for (int r = 0; r < 4; ++r)
      bars[(size_t)blockIdx.x * 1024 + r * 256 + tid] = 0;
  }
}

// ---------------- launch ---------------------------------------------------
static void launch_fallback(const int* perm, float* out, char* wsb,
                            hipStream_t stream) {
  WSL w = ws_layout(wsb);
  k_prep2<<<K_ / 8, 256, 0, stream>>>(w.ls1, perm, w.ls2);
  for (int it = 0; it < NITER; ++it) {
    const int pr = it & 1;
    const int wm = (it == 0) ? 0 : 2;
    const int wrS = (it != NITER - 1) ? 1 : 0;
    unsigned long long* S1r = pr ? w.S1b : w.S1a;
    unsigned long long* S1w = pr ? w.S1a : w.S1b;
    unsigned long long* T1r = pr ? w.T1b : w.T1a;
    unsigned long long* T1w = pr ? w.T1a : w.T1b;
    unsigned long long* S2r = pr ? w.S2b : w.S2a;
    unsigned long long* S2w = pr ? w.S2a : w.S2b;
    unsigned long long* T2r = pr ? w.T2b : w.T2a;
    unsigned long long* T2w = pr ? w.T2a : w.T2b;
    k_half<<<C_, 256, 0, stream>>>(w.gx1, w.gy1, w.ls1, w.inv, w.gx2,
                                   w.lpostT, S1r, S1w, T1r, T1w, wm, 0, wrS);
    k_half<<<C_, 256, 0, stream>>>(w.gx2, w.gy2, w.ls2, perm, w.gx1,
                                   w.lpostT, S2r, S2w, T2r, T2w, wm,
                                   (it == NITER - 1) ? 1 : 0, wrS);
  }
  k_out<<<dim3(K_ / 64, B_ / 64), 256, 0, stream>>>(w.lpostT, out);
}

extern "C" void kernel_launch(void* const* d_in, const int* in_sizes, int n_in,
                              void* d_out, int out_size, void* d_ws, size_t ws_size,
                              hipStream_t stream) {
  (void)in_sizes; (void)n_in; (void)out_size; (void)ws_size;
  const float* inp = (const float*)d_in[0];
  const int* perm = (const int*)d_in[1];
  float* out = (float*)d_out;
  char* wsb = (char*)d_ws;
  WSL w = ws_layout(wsb);

  k_prep1<<<dim3(K_ / 64, B_ / 64), 256, 0, stream>>>(
      inp, perm, w.gx1, w.ls1, w.gy1, w.gy2, w.inv, w.bars);

  // mode: 0 = undecided, 1 = persistent plain-launch, 2 = fallback.
  // The persistent kernel needs all blocks co-resident: guaranteed by
  // grid <= maxActiveBlocksPerCU x CUs (64 VGPR / no LDS -> 8 blocks/CU,
  // so grid=1024 uses half of capacity). No cooperative API involved.
  static int g_mode = 0;
  static int g_grid = 0;

  if (g_mode == 0) {
    int nb = 0;
    if (hipOccupancyMaxActiveBlocksPerMultiprocessor(&nb, k_fused, 256, 0)
            != hipSuccess)
      nb = 0;
    int ncu = 0;
    hipDeviceProp_t prop;
    int dev = 0;
    (void)hipGetDevice(&dev);
    if (hipGetDeviceProperties(&prop, dev) == hipSuccess)
      ncu = prop.multiProcessorCount;
    long long g = (long long)nb * (long long)ncu;
    int grid = (g > C_) ? C_ : (int)g;
    grid &= ~31;                          // tree barrier needs grid % 32 == 0
    if (grid >= 32) { g_mode = 1; g_grid = grid; }
    else            { g_mode = 2; }
  }

  if (g_mode == 1) {
    k_fused<<<g_grid, 256, 0, stream>>>(perm, wsb);
    k_out<<<dim3(K_ / 64, B_ / 64), 256, 0, stream>>>(w.lpostT, out);
  } else {
    launch_fallback(perm, out, wsb, stream);
  }
}

// Round 7
// 212.651 us; speedup vs baseline: 1.6282x; 1.1458x over previous
//
#include <hip/hip_runtime.h>
#include <hip/hip_fp16.h>

// ---------------- problem constants ----------------
constexpr int B_ = 256;        // batch
constexpr int K_ = 6144;       // block length
constexpr int NITER = 6;
constexpr int L_ = 6;          // window valid length
constexpr int W0_ = 6;         // uniform-init warmup (iteration 0)
constexpr int C_ = K_ / L_;    // chunks = 1024
constexpr int CPB = 4;         // chunks per persistent block (1024 threads)
constexpr int GRID = C_ / CPB; // 256 blocks = 1/CU
constexpr float LOG2E = 1.4426950408889634f;
constexpr float LN2   = 0.6931471805599453f;

static_assert(K_ % L_ == 0, "");
static_assert((L_ % 2) == 0 && (W0_ % 2) == 0, "");
static_assert(W0_ <= L_, "uniform-warmup trick requires W0 <= L");
static_assert(C_ % CPB == 0, "");

#if __has_builtin(__builtin_amdgcn_exp2f)
#define EXP2F(x) __builtin_amdgcn_exp2f(x)
#else
#define EXP2F(x) exp2f(x)
#endif
#if __has_builtin(__builtin_amdgcn_logf)
#define LOG2F(x) __builtin_amdgcn_logf(x)
#else
#define LOG2F(x) log2f(x)
#endif
#if __has_builtin(__builtin_amdgcn_rcpf)
#define RCPF(x) __builtin_amdgcn_rcpf(x)
#else
#define RCPF(x) (1.0f / (x))
#endif

// ---- bf16 scalar helpers (RNE) ----
__device__ __forceinline__ float b2f(unsigned short u) {
  return __uint_as_float((unsigned)u << 16);
}
__device__ __forceinline__ unsigned short f2b(float f) {
  unsigned u = __float_as_uint(f);
  u += 0x7FFFu + ((u >> 16) & 1u);
  return (unsigned short)(u >> 16);
}
// fp16 bit helpers
__device__ __forceinline__ float h2f_bits(unsigned short us) {
  __half_raw r; r.x = us; return __half2float(__half(r));
}
__device__ __forceinline__ unsigned short f2h_bits(float f) {
  return __half_as_ushort(__float2half(f));
}

// ---- agent-scope (cross-XCD) relaxed accessors: sc1 ops bypass the
// non-coherent per-XCD L2s and hit the device coherence point (MALL).
// Proven round-4/6 protocol: producers sc1 write-through; every wave's
// stores drain at __syncthreads (compiler emits vmcnt(0) before s_barrier);
// consumers sc1-load. NO buffer_wbl2/buffer_inv anywhere, so read-only
// planes (gy/ls/inv/perm) stay L2-resident across all phases.
__device__ __forceinline__ unsigned int ld_dev_u32(const unsigned int* p) {
  return __hip_atomic_load(const_cast<unsigned int*>(p), __ATOMIC_RELAXED,
                           __HIP_MEMORY_SCOPE_AGENT);
}
__device__ __forceinline__ void st_dev_u32(unsigned int* p, unsigned int v) {
  __hip_atomic_store(p, v, __ATOMIC_RELAXED, __HIP_MEMORY_SCOPE_AGENT);
}
__device__ __forceinline__ float ld_dev_f32(const float* p) {
  return __hip_atomic_load(const_cast<float*>(p), __ATOMIC_RELAXED,
                           __HIP_MEMORY_SCOPE_AGENT);
}
__device__ __forceinline__ void st_dev_f32(float* p, float v) {
  __hip_atomic_store(p, v, __ATOMIC_RELAXED, __HIP_MEMORY_SCOPE_AGENT);
}
__device__ __forceinline__ unsigned long long ld_dev_u64(
    const unsigned long long* p) {
  return __hip_atomic_load(const_cast<unsigned long long*>(p),
                           __ATOMIC_RELAXED, __HIP_MEMORY_SCOPE_AGENT);
}
__device__ __forceinline__ void st_dev_u64(unsigned long long* p,
                                           unsigned long long v) {
  __hip_atomic_store(p, v, __ATOMIC_RELAXED, __HIP_MEMORY_SCOPE_AGENT);
}

// trellis: fb(s,u)=u^s1^s0, nxt(s,u)=(fb<<2)|(s>>1), par(s,u)=u^s1^s2
__device__ __forceinline__ void gam_lin(float gxv, float gyv, float g[4]) {
  float es = EXP2F(-fabsf(gxv));
  float ep = EXP2F(-fabsf(gyv));
  float fu0 = gxv >= 0.0f ? 1.0f : es;
  float fu1 = gxv >= 0.0f ? es : 1.0f;
  float fp0 = gyv >= 0.0f ? 1.0f : ep;
  float fp1 = gyv >= 0.0f ? ep : 1.0f;
  g[0] = fu0 * fp0; g[1] = fu0 * fp1;
  g[2] = fu1 * fp0; g[3] = fu1 * fp1;
}

__device__ __forceinline__ void step_fwd_lin(float a[8], const float g[4]) {
  float an[8];
#pragma unroll
  for (int sn = 0; sn < 8; ++sn) {
    const int u0 = ((sn >> 2) ^ (sn & 1)) & 1;
    const int p0 = ((sn >> 2) ^ ((sn >> 1) & 1)) & 1;
    an[sn] = a[(sn & 3) * 2] * g[u0 * 2 + p0]
           + a[(sn & 3) * 2 + 1] * g[(u0 ^ 1) * 2 + (p0 ^ 1)];
  }
#pragma unroll
  for (int s = 0; s < 8; ++s) a[s] = an[s];
}

__device__ __forceinline__ void step_bwd_lin(float bt[8], const float g[4]) {
  float bn[8];
#pragma unroll
  for (int s = 0; s < 8; ++s) {
    const int s0 = s & 1, s1b = (s >> 1) & 1, s2b = (s >> 2) & 1;
    const int f0 = s1b ^ s0, q = s1b ^ s2b;
    bn[s] = g[q] * bt[(f0 << 2) | (s >> 1)]
          + g[2 + (q ^ 1)] * bt[((f0 ^ 1) << 2) | (s >> 1)];
  }
#pragma unroll
  for (int s = 0; s < 8; ++s) bt[s] = bn[s];
}

// max-renorm with tiny floor injection: NaN/underflow-proof
__device__ __forceinline__ void renorm_lin(float a[8]) {
  float m = fmaxf(fmaxf(fmaxf(a[0], a[1]), fmaxf(a[2], a[3])),
                  fmaxf(fmaxf(a[4], a[5]), fmaxf(a[6], a[7])));
  float r = RCPF(fmaxf(m, 1e-30f));
#pragma unroll
  for (int s = 0; s < 8; ++s) a[s] = fmaf(a[s], r, 1e-32f);
}

// ---- log8-packed boundary states: u8 = round(-16*log2(x)), clamp 255. ----
__device__ __forceinline__ unsigned long long pack8_log8(const float a[8]) {
  unsigned int us[8];
#pragma unroll
  for (int s = 0; s < 8; ++s) {
    float l = -16.0f * LOG2F(a[s]);
    l = fminf(l, 255.0f);
    us[s] = (unsigned int)(l + 0.5f);
  }
  unsigned int x = us[0] | (us[1] << 8) | (us[2] << 16) | (us[3] << 24);
  unsigned int y = us[4] | (us[5] << 8) | (us[6] << 16) | (us[7] << 24);
  return ((unsigned long long)y << 32) | x;
}

__device__ __forceinline__ void unpack8_log8(unsigned long long v, float a[8]) {
  unsigned int vx = (unsigned int)v, vy = (unsigned int)(v >> 32);
#pragma unroll
  for (int s = 0; s < 4; ++s)
    a[s] = EXP2F(-0.0625f * (float)((vx >> (8 * s)) & 0xFFu));
#pragma unroll
  for (int s = 0; s < 4; ++s)
    a[4 + s] = EXP2F(-0.0625f * (float)((vy >> (8 * s)) & 0xFFu));
}

// ---------------- tree barrier geometry -----------------------------------
// Per slot: 32 group-counter lines + 32 release lines + 1 root line, each
// 128 B. Arrive: leader RMWs its group line; group-finisher RMWs root;
// root-finisher stores the 32 release flags. Pollers only read release
// lines. (Proven round 4/6; now only 256 leaders -> 8 per group line.)
constexpr int NSLOT = 2 * NITER;           // 11 phase barriers + pre-out
constexpr int SLOT_U = 65 * 32;            // uints per slot
constexpr int BARS_U = 28672;              // alloc (>= NSLOT*SLOT_U = 24960)

__device__ __forceinline__ void tree_barrier(unsigned int* slotBase,
                                             unsigned int gsz) {
  __syncthreads();                         // each wave drains vmcnt here
  if (threadIdx.x == 0) {
    asm volatile("s_waitcnt vmcnt(0)" ::: "memory");
    const unsigned int g = blockIdx.x & 31u;
    unsigned int* cnt = slotBase + g * 32;
    unsigned int* rel = slotBase + (32 + g) * 32;
    unsigned int* root = slotBase + 64 * 32;
    unsigned int m = __hip_atomic_fetch_add(cnt, 1u, __ATOMIC_RELAXED,
                                            __HIP_MEMORY_SCOPE_AGENT);
    if (m == gsz - 1u) {                   // last of group -> root
      unsigned int r = __hip_atomic_fetch_add(root, 1u, __ATOMIC_RELAXED,
                                              __HIP_MEMORY_SCOPE_AGENT);
      if (r == 31u) {                      // last group -> broadcast release
#pragma unroll
        for (int gg = 0; gg < 32; ++gg)
          st_dev_u32(slotBase + (32 + gg) * 32, 1u);
      }
    }
    while (!ld_dev_u32(rel))
      __builtin_amdgcn_s_sleep(2);
  }
  __syncthreads();
}

// ---------------- workspace layout (shared host/device) -------------------
struct WSL {
  float* lpostT;
  __half* gx1; __half* gx2;            // fp16 extrinsic planes, PAIR-PACKED:
                                       // u32 at [j*(B/2)+(b>>1)] = cols b,b+1
  unsigned short* gy1; unsigned short* gy2;
  __half* ls1; __half* ls2;
  int* inv;
  unsigned int* bars;
  unsigned long long *S1a, *S1b, *T1a, *T1b, *S2a, *S2b, *T2a, *T2b;
};

__host__ __device__ inline WSL ws_layout(char* ws) {
  const size_t KB = (size_t)K_ * B_;
  WSL w; char* p = ws;
  w.lpostT = (float*)p;            p += KB * 4;
  w.gx1    = (__half*)p;           p += KB * 2;
  w.gx2    = (__half*)p;           p += KB * 2;
  w.gy1    = (unsigned short*)p;   p += KB * 2;
  w.gy2    = (unsigned short*)p;   p += KB * 2;
  w.ls1    = (__half*)p;           p += KB * 2;
  w.ls2    = (__half*)p;           p += KB * 2;
  w.inv    = (int*)p;              p += (size_t)K_ * 4;
  w.bars   = (unsigned int*)p;     p += (size_t)BARS_U * 4;
  const size_t SB = (size_t)(C_ + 1) * B_;          // ull elements
  w.S1a = (unsigned long long*)p;  p += SB * 8;
  w.S1b = (unsigned long long*)p;  p += SB * 8;
  w.T1a = (unsigned long long*)p;  p += SB * 8;
  w.T1b = (unsigned long long*)p;  p += SB * 8;
  w.S2a = (unsigned long long*)p;  p += SB * 8;
  w.S2b = (unsigned long long*)p;  p += SB * 8;
  w.T2a = (unsigned long long*)p;  p += SB * 8;
  w.T2b = (unsigned long long*)p;  p += SB * 8;
  return w;                                          // ~42.2 MB total
}

// ---------------- one windowed BCJR half-iteration (linear domain) --------
// DEV=true: persistent-kernel phase; exchanged planes use sc1 ops, except
// gxc (gx produced by a prior dispatch -> plain cached reads). Block-interior
// S/T boundaries route through LDS (lds_* non-null) -- same log8 codec, so
// values are bit-identical to the global round-trip. DEV=false: fallback
// (all lds_* null, plain global).
template <bool DEV>
__device__ __forceinline__ void half_body(
    const int c,
    const __half* __restrict__ gx,
    const unsigned short* __restrict__ gy,
    const __half* __restrict__ lsloc,
    const int* __restrict__ map,
    __half* __restrict__ gxother,
    float* __restrict__ lpost_out,
    const unsigned long long* __restrict__ Sread,
    unsigned long long* __restrict__ Swrite,
    const unsigned long long* __restrict__ Tread,
    unsigned long long* __restrict__ Twrite,
    const unsigned long long* lds_sr, unsigned long long* lds_sw,
    const unsigned long long* lds_tr, unsigned long long* lds_tw,
    int b, int wmode, int mode, int wrS, bool gxc) {
  const int kv = c * L_;
  const int kend = kv + L_;
  const unsigned int* gxp = (const unsigned int*)gx;   // packed [K][B/2]
  const int bh = b >> 1;
  const unsigned int hsel = (b & 1) * 16;              // shift for my half
  const bool gdev = DEV && !gxc;

  // ---- issue ALL independent loads upfront ----
  float gvx[L_];
  unsigned short rgy[L_];
  __half hls[L_];
#pragma unroll
  for (int i = 0; i < L_; ++i) {
    size_t o2 = (size_t)(kv + i) * (B_ / 2) + bh;
    unsigned int u = gdev ? ld_dev_u32(gxp + o2) : gxp[o2];
    gvx[i] = h2f_bits((unsigned short)(u >> hsel));
    rgy[i] = gy[(size_t)(kv + i) * B_ + b];
  }
  if (mode == 0) {
#pragma unroll
    for (int i = 0; i < L_; ++i)
      hls[i] = lsloc[(size_t)(kv + i) * B_ + b];   // local rows, cached
  }
  int jmap[L_];
#pragma unroll
  for (int i = 0; i < L_; ++i) jmap[i] = map[kv + i];     // group-uniform
  unsigned long long sraw = 0, traw = 0;
  float wfx[W0_], wbx[W0_];
  unsigned short wfy[W0_], wby[W0_];
  if (wmode == 2) {
    if (c > 0) {
      if (lds_sr) sraw = *lds_sr;
      else {
        const size_t o = (size_t)c * B_ + b;
        sraw = DEV ? ld_dev_u64(Sread + o) : Sread[o];
      }
    }
    if (c < C_ - 1) {
      if (lds_tr) traw = *lds_tr;
      else {
        const size_t o = (size_t)(c + 1) * B_ + b;
        traw = DEV ? ld_dev_u64(Tread + o) : Tread[o];
      }
    }
  } else {
    // warmup gammas, all upfront (wu == W0_ exactly, since kv >= W0_ at c>=1)
    if (c > 0) {
#pragma unroll
      for (int q = 0; q < W0_; ++q) {
        size_t o2 = (size_t)(kv - W0_ + q) * (B_ / 2) + bh;
        unsigned int u = gdev ? ld_dev_u32(gxp + o2) : gxp[o2];
        wfx[q] = h2f_bits((unsigned short)(u >> hsel));
        wfy[q] = gy[(size_t)(kv - W0_ + q) * B_ + b];
      }
    }
    if (c < C_ - 1) {
#pragma unroll
      for (int q = 0; q < W0_; ++q) {
        size_t o2 = (size_t)(kend + W0_ - 1 - q) * (B_ / 2) + bh;
        unsigned int u = gdev ? ld_dev_u32(gxp + o2) : gxp[o2];
        wbx[q] = h2f_bits((unsigned short)(u >> hsel));
        wby[q] = gy[(size_t)(kend + W0_ - 1 - q) * B_ + b];
      }
    }
  }

  // ---- valid gammas (gvx kept: needed for extrinsic) ----
  float gc[L_][4];
#pragma unroll
  for (int i = 0; i < L_; ++i) gam_lin(gvx[i], b2f(rgy[i]), gc[i]);

  // ---------------- forward ----------------
  float a[8];
  if (c == 0) {
    a[0] = 1.0f;
#pragma unroll
    for (int s = 1; s < 8; ++s) a[s] = 0.0f;
  } else if (wmode == 0) {
    if (c == 1) {                    // warmup starts at position 0: exact init
      a[0] = 1.0f;
#pragma unroll
      for (int s = 1; s < 8; ++s) a[s] = 0.0f;
    } else {
#pragma unroll
      for (int s = 0; s < 8; ++s) a[s] = 1.0f;
    }
#pragma unroll
    for (int q = 0; q < W0_; ++q) {
      float g[4];
      gam_lin(wfx[q], b2f(wfy[q]), g);
      step_fwd_lin(a, g);
      if (q & 1) renorm_lin(a);
    }
  } else {
    unpack8_log8(sraw, a);           // pure inheritance (c>0 here)
  }
  // valid region: record alpha, then step (all L steps -> a = alpha(kend))
  float a2d[L_][8];
#pragma unroll
  for (int i = 0; i < L_; ++i) {
#pragma unroll
    for (int s = 0; s < 8; ++s) a2d[i][s] = a[s];
    step_fwd_lin(a, gc[i]);
    if (i & 1) renorm_lin(a);
  }
  if (wrS) {
    unsigned long long v = pack8_log8(a);
    if (lds_sw) *lds_sw = v;
    else {
      unsigned long long* p = Swrite + (size_t)(c + 1) * B_ + b;
      if (DEV) st_dev_u64(p, v); else *p = v;
    }
  }

  // ---------------- backward + posterior ----------------
  float bt[8];
  if (c == C_ - 1) {
#pragma unroll
    for (int s = 0; s < 8; ++s) bt[s] = 1.0f;    // exact tail init (uniform)
  } else if (wmode == 0) {
#pragma unroll
    for (int s = 0; s < 8; ++s) bt[s] = 1.0f;    // uniform (exact at c=C_-2)
#pragma unroll
    for (int q = 0; q < W0_; ++q) {
      float g[4];
      gam_lin(wbx[q], b2f(wby[q]), g);
      step_bwd_lin(bt, g);
      if (q & 1) renorm_lin(bt);
    }
  } else {
    unpack8_log8(traw, bt);          // pure inheritance (c<C_-1 here)
  }
  // valid region, descending: posterior + extrinsic + beta step
#pragma unroll
  for (int ii = 0; ii < L_; ++ii) {
    const int i = L_ - 1 - ii;
    const float* g = gc[i];
    float s00 = 0.0f, s01 = 0.0f, s10 = 0.0f, s11 = 0.0f;
    float bn[8];
#pragma unroll
    for (int s = 0; s < 8; ++s) {
      const int s0 = s & 1, s1b = (s >> 1) & 1, s2b = (s >> 2) & 1;
      const int f0 = s1b ^ s0, q = s1b ^ s2b;
      float b0 = bt[(f0 << 2) | (s >> 1)];
      float b1 = bt[((f0 ^ 1) << 2) | (s >> 1)];
      float m0 = a2d[i][s] * b0;
      float m1 = a2d[i][s] * b1;
      if (q == 0) { s00 += m0; s10 += m1; } else { s01 += m0; s11 += m1; }
      bn[s] = g[q] * b0 + g[2 + (q ^ 1)] * b1;
    }
    float t0 = g[0] * s00 + g[1] * s01;
    float t1 = g[3] * s10 + g[2] * s11;
    float lpost = LOG2F(fmaxf(t0, 1e-37f)) - LOG2F(fmaxf(t1, 1e-37f));
    if (mode == 0) {
      float le = lpost - gvx[i];                 // lpost - (ls + la)
      unsigned short us = f2h_bits(__half2float(hls[i]) + le);
      // quad-pack with lane partners (jmap row uniform across the group):
      // pair via shfl_xor(1), then two pairs via shfl_xor(2) -> one u64
      // store per 4 lanes (half the sc1 stores, 8B granularity).
      unsigned int po = (unsigned int)__shfl_xor((int)us, 1);
      unsigned int u32v = (b & 1) ? (po | ((unsigned int)us << 16))
                                  : ((unsigned int)us | (po << 16));
      unsigned int uhi = (unsigned int)__shfl_xor((int)u32v, 2);
      if ((b & 3) == 0) {
        unsigned long long v64 =
            (unsigned long long)u32v | ((unsigned long long)uhi << 32);
        unsigned long long* p =
            (unsigned long long*)gxother + ((size_t)jmap[i] * (B_ / 4) + (b >> 2));
        if (DEV) st_dev_u64(p, v64); else *p = v64;
      }
    } else {
      float v = -LN2 * lpost;                    // final value, row perm[kk]
      float* p = lpost_out + ((size_t)jmap[i] * B_ + b);
      if (DEV) st_dev_f32(p, v); else *p = v;    // sc1: read by out-phase
    }
#pragma unroll
    for (int s = 0; s < 8; ++s) bt[s] = bn[s];
    if (ii & 1) renorm_lin(bt);
  }
  if (wrS) {
    unsigned long long v = pack8_log8(bt);
    if (lds_tw) *lds_tw = v;
    else {
      unsigned long long* p = Twrite + (size_t)c * B_ + b;
      if (DEV) st_dev_u64(p, v); else *p = v;
    }
  }
}

// ---------------- persistent megakernel (plain launch) --------------------
// 1024-thread blocks own 4 consecutive chunks (q = tid>>8). 3/4 of S/T
// boundaries are block-interior -> LDS ping-pong (global S/T traffic /4).
// Final phase: out-transpose (LDS tile aliased onto dead S/T buffers).
__global__ __launch_bounds__(1024, 4) void k_fused(const int* __restrict__ perm,
                                                   float* __restrict__ out,
                                                   char* __restrict__ ws) {
  WSL w = ws_layout(ws);
  // [S=0/T=1][dec][pingpong][boundary 0..2][b]  = 49152 B
  __shared__ unsigned long long ldsST[2][2][2][3][256];
  const int tid = threadIdx.x;
  const int q = tid >> 8;                    // chunk slot in block
  const int b = tid & 255;
  const int c = blockIdx.x * CPB + q;
  const unsigned int gsz = gridDim.x >> 5;   // blocks per barrier group

  // prologue: ls2 gather for own chunk rows (read back by the SAME block ->
  // plain cached, no barrier needed).
#pragma unroll
  for (int r = 0; r < L_; ++r) {
    const int j = c * L_ + r;
    w.ls2[(size_t)j * B_ + b] = w.ls1[(size_t)perm[j] * B_ + b];
  }

  int slot = 0;
  for (int it = 0; it < NITER; ++it) {
    const int pr = it & 1, pw = pr ^ 1;
    const int wm = (it == 0) ? 0 : 2;
    const int wrS = (it != NITER - 1) ? 1 : 0;
    unsigned long long* S1r = pr ? w.S1b : w.S1a;
    unsigned long long* S1w = pr ? w.S1a : w.S1b;
    unsigned long long* T1r = pr ? w.T1b : w.T1a;
    unsigned long long* T1w = pr ? w.T1a : w.T1b;
    unsigned long long* S2r = pr ? w.S2b : w.S2a;
    unsigned long long* S2w = pr ? w.S2a : w.S2b;
    unsigned long long* T2r = pr ? w.T2b : w.T2a;
    unsigned long long* T2w = pr ? w.T2a : w.T2b;
    // phase 0 (decoder 1): extrinsic -> gx2[inv[kk]]; local ls plane = ls1.
    // gx1 holds prep1's packed fp16 ls values at it0 (la=0) -> cached reads.
    half_body<true>(c, w.gx1, w.gy1, w.ls1, w.inv, w.gx2, w.lpostT,
                    S1r, S1w, T1r, T1w,
                    (q > 0) ? &ldsST[0][0][pr][q - 1][b] : nullptr,
                    (q < 3) ? &ldsST[0][0][pw][q][b] : nullptr,
                    (q < 3) ? &ldsST[1][0][pr][q][b] : nullptr,
                    (q > 0) ? &ldsST[1][0][pw][q - 1][b] : nullptr,
                    b, wm, 0, wrS, it == 0);
    tree_barrier(w.bars + slot * SLOT_U, gsz); ++slot;
    // phase 1 (decoder 2): extrinsic -> gx1[perm[kk]]; local ls plane = ls2
    half_body<true>(c, w.gx2, w.gy2, w.ls2, perm, w.gx1, w.lpostT,
                    S2r, S2w, T2r, T2w,
                    (q > 0) ? &ldsST[0][1][pr][q - 1][b] : nullptr,
                    (q < 3) ? &ldsST[0][1][pw][q][b] : nullptr,
                    (q < 3) ? &ldsST[1][1][pr][q][b] : nullptr,
                    (q > 0) ? &ldsST[1][1][pw][q - 1][b] : nullptr,
                    b, wm, (it == NITER - 1) ? 1 : 0, wrS, false);
    tree_barrier(w.bars + slot * SLOT_U, gsz); ++slot;
  }

  // ---- out-phase: out[b,i] = lpostT[i,b]. S/T LDS is dead -> alias the
  // transpose tile onto it. lpostT was sc1-written -> sc1 reads (its lines
  // are never in L2: only ever touched via sc1 in this kernel).
  float* tt = reinterpret_cast<float*>(&ldsST[0][0][0][0][0]);  // 64x65
  for (int t = blockIdx.x; t < (K_ / 64) * (B_ / 64); t += gridDim.x) {
    const int i0 = (t >> 2) * 64;      // t / (B_/64)
    const int b0 = (t & 3) * 64;       // t % (B_/64)
    __syncthreads();                   // protect LDS tile reuse
    const int tb = tid & 63, iq = tid >> 6;    // iq 0..15
    for (int ii = iq; ii < 64; ii += 16)
      tt[ii * 65 + tb] =
          ld_dev_f32(w.lpostT + (size_t)(i0 + ii) * B_ + (b0 + tb));
    __syncthreads();
    for (int bb = iq; bb < 64; bb += 16)
      out[(size_t)(b0 + bb) * K_ + (i0 + tb)] = tt[tb * 65 + bb];
  }
}

// ---------------- fallback kernels (proven multi-launch path) -------------
__global__ __launch_bounds__(256, 4) void k_half(
    const __half* __restrict__ gx, const unsigned short* __restrict__ gy,
    const __half* __restrict__ lsloc, const int* __restrict__ map,
    __half* __restrict__ gxother, float* __restrict__ lpost_out,
    const unsigned long long* __restrict__ Sread,
    unsigned long long* __restrict__ Swrite,
    const unsigned long long* __restrict__ Tread,
    unsigned long long* __restrict__ Twrite,
    int wmode, int mode, int wrS) {
  half_body<false>(blockIdx.x, gx, gy, lsloc, map, gxother, lpost_out,
                   Sread, Swrite, Tread, Twrite,
                   nullptr, nullptr, nullptr, nullptr,
                   threadIdx.x, wmode, mode, wrS, true);
}

__global__ __launch_bounds__(256) void k_prep2(const __half* __restrict__ ls1,
                                               const int* __restrict__ perm,
                                               __half* __restrict__ ls2) {
  const int b = threadIdx.x;
#pragma unroll
  for (int r = 0; r < 8; ++r) {
    const int j = blockIdx.x * 8 + r;
    ls2[(size_t)j * B_ + b] = ls1[(size_t)perm[j] * B_ + b];
  }
}

__global__ __launch_bounds__(256) void k_out(const float* __restrict__ lpostT,
                                             float* __restrict__ out) {
  __shared__ float t[64][65];
  const int tid = threadIdx.x;
  const int i0 = blockIdx.x * 64, b0 = blockIdx.y * 64;
  const int tb = tid & 63, iq = tid >> 6;
  for (int ii = iq; ii < 64; ii += 4) {
    t[ii][tb] = lpostT[(size_t)(i0 + ii) * B_ + (b0 + tb)];
  }
  __syncthreads();
  const int ik = tid & 63, bq = tid >> 6;
  for (int bb = bq; bb < 64; bb += 4) {
    out[(size_t)(b0 + bb) * K_ + (i0 + ik)] = t[ik][bb];
  }
}

// ---------------- prep: de-interleave + transpose + scale to log2 domain --
// Also: writes pair-packed fp16 ls into gx1 (it0 phase-0 gamma plane, la=0),
// computes inv, and zeroes the barrier region (kernel-end flush publishes
// everything for the persistent kernel).
__global__ __launch_bounds__(256) void k_prep1(const float* __restrict__ inp,
                                               const int* __restrict__ perm,
                                               __half* __restrict__ gx1,
                                               __half* __restrict__ ls1,
                                               unsigned short* __restrict__ gy1,
                                               unsigned short* __restrict__ gy2,
                                               int* __restrict__ inv,
                                               unsigned int* __restrict__ bars) {
  __shared__ float t[3][64][65];
  const int tid = threadIdx.x;
  const int k0 = blockIdx.x * 64, b0 = blockIdx.y * 64;
  const int tk = tid & 63, tq = tid >> 6;
  for (int bb = tq; bb < 64; bb += 4) {
    size_t base = (size_t)(b0 + bb) * (3 * K_) + 3 * (size_t)(k0 + tk);
    t[0][bb][tk] = inp[base + 0];
    t[1][bb][tk] = inp[base + 1];
    t[2][bb][tk] = inp[base + 2];
  }
  __syncthreads();
  const int tb = tid & 63, kq = tid >> 6;
  for (int kk = kq; kk < 64; kk += 4) {
    size_t o = (size_t)(k0 + kk) * B_ + (b0 + tb);
    float sv = -LOG2E * t[0][tb][kk];
    float p1 = -LOG2E * t[1][tb][kk];
    float p2 = -LOG2E * t[2][tb][kk];
    ls1[o] = __float2half(sv);
    gy1[o] = f2b(p1);
    gy2[o] = f2b(p2);
    if (!(tb & 1)) {                      // pair-packed gx1 (cols tb, tb+1)
      float sv1 = -LOG2E * t[0][tb + 1][kk];
      unsigned int u = (unsigned int)f2h_bits(sv) |
                       ((unsigned int)f2h_bits(sv1) << 16);
      ((unsigned int*)gx1)[o >> 1] = u;
    }
  }
  if (blockIdx.y == 0 && tid < 64) {
    const int j = k0 + tid;
    inv[perm[j]] = j;
  }
  if (blockIdx.y == 1 && blockIdx.x < BARS_U / 1024) {   // zero barrier region
#pragma unroll
    for (int r = 0; r < 4; ++r)
      bars[(size_t)blockIdx.x * 1024 + r * 256 + tid] = 0;
  }
}

// ---------------- launch ---------------------------------------------------
static void launch_fallback(const int* perm, float* out, char* wsb,
                            hipStream_t stream) {
  WSL w = ws_layout(wsb);
  k_prep2<<<K_ / 8, 256, 0, stream>>>(w.ls1, perm, w.ls2);
  for (int it = 0; it < NITER; ++it) {
    const int pr = it & 1;
    const int wm = (it == 0) ? 0 : 2;
    const int wrS = (it != NITER - 1) ? 1 : 0;
    unsigned long long* S1r = pr ? w.S1b : w.S1a;
    unsigned long long* S1w = pr ? w.S1a : w.S1b;
    unsigned long long* T1r = pr ? w.T1b : w.T1a;
    unsigned long long* T1w = pr ? w.T1a : w.T1b;
    unsigned long long* S2r = pr ? w.S2b : w.S2a;
    unsigned long long* S2w = pr ? w.S2a : w.S2b;
    unsigned long long* T2r = pr ? w.T2b : w.T2a;
    unsigned long long* T2w = pr ? w.T2a : w.T2b;
    k_half<<<C_, 256, 0, stream>>>(w.gx1, w.gy1, w.ls1, w.inv, w.gx2,
                                   w.lpostT, S1r, S1w, T1r, T1w, wm, 0, wrS);
    k_half<<<C_, 256, 0, stream>>>(w.gx2, w.gy2, w.ls2, perm, w.gx1,
                                   w.lpostT, S2r, S2w, T2r, T2w, wm,
                                   (it == NITER - 1) ? 1 : 0, wrS);
  }
  k_out<<<dim3(K_ / 64, B_ / 64), 256, 0, stream>>>(w.lpostT, out);
}

extern "C" void kernel_launch(void* const* d_in, const int* in_sizes, int n_in,
                              void* d_out, int out_size, void* d_ws, size_t ws_size,
                              hipStream_t stream) {
  (void)in_sizes; (void)n_in; (void)out_size; (void)ws_size;
  const float* inp = (const float*)d_in[0];
  const int* perm = (const int*)d_in[1];
  float* out = (float*)d_out;
  char* wsb = (char*)d_ws;
  WSL w = ws_layout(wsb);

  k_prep1<<<dim3(K_ / 64, B_ / 64), 256, 0, stream>>>(
      inp, perm, w.gx1, w.ls1, w.gy1, w.gy2, w.inv, w.bars);

  // mode: 0 = undecided, 1 = persistent plain-launch, 2 = fallback.
  // Co-residency: GRID=256 1024-thread blocks; occupancy cap = min(2048
  // thr/CU, 160KB/48KB LDS) = 2 blocks/CU -> 512 slots >= 256. Verified via
  // the occupancy API; no cooperative API involved (no grid.sync used).
  static int g_mode = 0;

  if (g_mode == 0) {
    int nb = 0;
    if (hipOccupancyMaxActiveBlocksPerMultiprocessor(&nb, k_fused, 1024, 0)
            != hipSuccess)
      nb = 0;
    int ncu = 0;
    hipDeviceProp_t prop;
    int dev = 0;
    (void)hipGetDevice(&dev);
    if (hipGetDeviceProperties(&prop, dev) == hipSuccess)
      ncu = prop.multiProcessorCount;
    g_mode = ((long long)nb * ncu >= GRID && (GRID % 32) == 0) ? 1 : 2;
  }

  if (g_mode == 1) {
    k_fused<<<GRID, 1024, 0, stream>>>(perm, out, wsb);
  } else {
    launch_fallback(perm, out, wsb, stream);
  }
}

// Round 8
// 210.503 us; speedup vs baseline: 1.6448x; 1.0102x over previous
//
#include <hip/hip_runtime.h>
#include <hip/hip_fp16.h>

// ---------------- problem constants ----------------
constexpr int B_ = 256;        // batch
constexpr int K_ = 6144;       // block length
constexpr int NITER = 6;
constexpr int L_ = 6;          // window valid length
constexpr int W0_ = 6;         // uniform-init warmup (iteration 0)
constexpr int C_ = K_ / L_;    // chunks = 1024
constexpr int CPB = 4;         // chunks per persistent block (1024 threads)
constexpr int GRID = C_ / CPB; // 256 blocks = 1/CU
constexpr int NTILE = (K_ / 64) * (B_ / 64);   // 384 prep/out tiles
constexpr float LOG2E = 1.4426950408889634f;
constexpr float LN2   = 0.6931471805599453f;

static_assert(K_ % L_ == 0, "");
static_assert((L_ % 2) == 0 && (W0_ % 2) == 0, "");
static_assert(W0_ <= L_, "uniform-warmup trick requires W0 <= L");
static_assert(C_ % CPB == 0, "");

#if __has_builtin(__builtin_amdgcn_exp2f)
#define EXP2F(x) __builtin_amdgcn_exp2f(x)
#else
#define EXP2F(x) exp2f(x)
#endif
#if __has_builtin(__builtin_amdgcn_logf)
#define LOG2F(x) __builtin_amdgcn_logf(x)
#else
#define LOG2F(x) log2f(x)
#endif
#if __has_builtin(__builtin_amdgcn_rcpf)
#define RCPF(x) __builtin_amdgcn_rcpf(x)
#else
#define RCPF(x) (1.0f / (x))
#endif

// ---- bf16 scalar helpers (RNE) ----
__device__ __forceinline__ float b2f(unsigned short u) {
  return __uint_as_float((unsigned)u << 16);
}
__device__ __forceinline__ unsigned short f2b(float f) {
  unsigned u = __float_as_uint(f);
  u += 0x7FFFu + ((u >> 16) & 1u);
  return (unsigned short)(u >> 16);
}
// fp16 bit helpers
__device__ __forceinline__ float h2f_bits(unsigned short us) {
  __half_raw r; r.x = us; return __half2float(__half(r));
}
__device__ __forceinline__ unsigned short f2h_bits(float f) {
  return __half_as_ushort(__float2half(f));
}

// ---- agent-scope (cross-XCD) relaxed accessors: sc1 ops bypass the
// non-coherent per-XCD L2s and hit the device coherence point (MALL).
// Proven round-4/6/7 protocol: producers sc1 write-through; waves drain at
// __syncthreads before the barrier arrive; consumers sc1-load. No
// buffer_wbl2/buffer_inv anywhere -> read-mostly planes stay L2-resident.
// NEW (r8): the in-kernel prep phase also writes via sc1; since kernel-start
// acquire invalidated all L2s, later PLAIN reads of those planes cold-miss
// to MALL (correct) and then cache normally.
__device__ __forceinline__ unsigned int ld_dev_u32(const unsigned int* p) {
  return __hip_atomic_load(const_cast<unsigned int*>(p), __ATOMIC_RELAXED,
                           __HIP_MEMORY_SCOPE_AGENT);
}
__device__ __forceinline__ void st_dev_u32(unsigned int* p, unsigned int v) {
  __hip_atomic_store(p, v, __ATOMIC_RELAXED, __HIP_MEMORY_SCOPE_AGENT);
}
__device__ __forceinline__ float ld_dev_f32(const float* p) {
  return __hip_atomic_load(const_cast<float*>(p), __ATOMIC_RELAXED,
                           __HIP_MEMORY_SCOPE_AGENT);
}
__device__ __forceinline__ void st_dev_f32(float* p, float v) {
  __hip_atomic_store(p, v, __ATOMIC_RELAXED, __HIP_MEMORY_SCOPE_AGENT);
}
__device__ __forceinline__ unsigned long long ld_dev_u64(
    const unsigned long long* p) {
  return __hip_atomic_load(const_cast<unsigned long long*>(p),
                           __ATOMIC_RELAXED, __HIP_MEMORY_SCOPE_AGENT);
}
__device__ __forceinline__ void st_dev_u64(unsigned long long* p,
                                           unsigned long long v) {
  __hip_atomic_store(p, v, __ATOMIC_RELAXED, __HIP_MEMORY_SCOPE_AGENT);
}

// trellis: fb(s,u)=u^s1^s0, nxt(s,u)=(fb<<2)|(s>>1), par(s,u)=u^s1^s2
__device__ __forceinline__ void gam_lin(float gxv, float gyv, float g[4]) {
  float es = EXP2F(-fabsf(gxv));
  float ep = EXP2F(-fabsf(gyv));
  float fu0 = gxv >= 0.0f ? 1.0f : es;
  float fu1 = gxv >= 0.0f ? es : 1.0f;
  float fp0 = gyv >= 0.0f ? 1.0f : ep;
  float fp1 = gyv >= 0.0f ? ep : 1.0f;
  g[0] = fu0 * fp0; g[1] = fu0 * fp1;
  g[2] = fu1 * fp0; g[3] = fu1 * fp1;
}

__device__ __forceinline__ void step_fwd_lin(float a[8], const float g[4]) {
  float an[8];
#pragma unroll
  for (int sn = 0; sn < 8; ++sn) {
    const int u0 = ((sn >> 2) ^ (sn & 1)) & 1;
    const int p0 = ((sn >> 2) ^ ((sn >> 1) & 1)) & 1;
    an[sn] = a[(sn & 3) * 2] * g[u0 * 2 + p0]
           + a[(sn & 3) * 2 + 1] * g[(u0 ^ 1) * 2 + (p0 ^ 1)];
  }
#pragma unroll
  for (int s = 0; s < 8; ++s) a[s] = an[s];
}

__device__ __forceinline__ void step_bwd_lin(float bt[8], const float g[4]) {
  float bn[8];
#pragma unroll
  for (int s = 0; s < 8; ++s) {
    const int s0 = s & 1, s1b = (s >> 1) & 1, s2b = (s >> 2) & 1;
    const int f0 = s1b ^ s0, q = s1b ^ s2b;
    bn[s] = g[q] * bt[(f0 << 2) | (s >> 1)]
          + g[2 + (q ^ 1)] * bt[((f0 ^ 1) << 2) | (s >> 1)];
  }
#pragma unroll
  for (int s = 0; s < 8; ++s) bt[s] = bn[s];
}

// max-renorm with tiny floor injection: NaN/underflow-proof
__device__ __forceinline__ void renorm_lin(float a[8]) {
  float m = fmaxf(fmaxf(fmaxf(a[0], a[1]), fmaxf(a[2], a[3])),
                  fmaxf(fmaxf(a[4], a[5]), fmaxf(a[6], a[7])));
  float r = RCPF(fmaxf(m, 1e-30f));
#pragma unroll
  for (int s = 0; s < 8; ++s) a[s] = fmaf(a[s], r, 1e-32f);
}

// ---- log8-packed boundary states (GLOBAL/exterior path; unchanged) ----
__device__ __forceinline__ unsigned long long pack8_log8(const float a[8]) {
  unsigned int us[8];
#pragma unroll
  for (int s = 0; s < 8; ++s) {
    float l = -16.0f * LOG2F(a[s]);
    l = fminf(l, 255.0f);
    us[s] = (unsigned int)(l + 0.5f);
  }
  unsigned int x = us[0] | (us[1] << 8) | (us[2] << 16) | (us[3] << 24);
  unsigned int y = us[4] | (us[5] << 8) | (us[6] << 16) | (us[7] << 24);
  return ((unsigned long long)y << 32) | x;
}

__device__ __forceinline__ void unpack8_log8(unsigned long long v, float a[8]) {
  unsigned int vx = (unsigned int)v, vy = (unsigned int)(v >> 32);
#pragma unroll
  for (int s = 0; s < 4; ++s)
    a[s] = EXP2F(-0.0625f * (float)((vx >> (8 * s)) & 0xFFu));
#pragma unroll
  for (int s = 0; s < 4; ++s)
    a[4 + s] = EXP2F(-0.0625f * (float)((vy >> (8 * s)) & 0xFFu));
}

// ---- fp16x8 boundary codec (LDS-interior path; r8): full-rate cvts
// replace quarter-rate log2/exp2. Values in (1e-32,1]; fp16 floor 6e-8
// (better than log8's 2^-15.9 clamp); sub-floor components round to 0
// which is numerically benign post-renorm.
__device__ __forceinline__ void pack8_h(const float a[8],
                                        unsigned long long o[2]) {
  unsigned int u[4];
#pragma unroll
  for (int k = 0; k < 4; ++k)
    u[k] = (unsigned int)f2h_bits(a[2 * k]) |
           ((unsigned int)f2h_bits(a[2 * k + 1]) << 16);
  o[0] = (unsigned long long)u[0] | ((unsigned long long)u[1] << 32);
  o[1] = (unsigned long long)u[2] | ((unsigned long long)u[3] << 32);
}
__device__ __forceinline__ void unpack8_h(unsigned long long v0,
                                          unsigned long long v1, float a[8]) {
  unsigned int u[4] = {(unsigned int)v0, (unsigned int)(v0 >> 32),
                       (unsigned int)v1, (unsigned int)(v1 >> 32)};
#pragma unroll
  for (int k = 0; k < 4; ++k) {
    a[2 * k] = h2f_bits((unsigned short)u[k]);
    a[2 * k + 1] = h2f_bits((unsigned short)(u[k] >> 16));
  }
}

// ---------------- tree barrier geometry -----------------------------------
// Per slot: 32 group-counter lines + 32 release lines + 1 root line, each
// 128 B. Proven round 4/6/7. Slots zeroed by a hipMemsetAsync dispatch
// preceding k_fused (kernel-boundary publish).
constexpr int NSLOT = 2 * NITER + 1;       // post-prep + 12 phase barriers
constexpr int SLOT_U = 65 * 32;
constexpr int BARS_U = 28672;              // >= NSLOT*SLOT_U = 27040

__device__ __forceinline__ void tree_barrier(unsigned int* slotBase,
                                             unsigned int gsz) {
  __syncthreads();                         // each wave drains vmcnt here
  if (threadIdx.x == 0) {
    asm volatile("s_waitcnt vmcnt(0)" ::: "memory");
    const unsigned int g = blockIdx.x & 31u;
    unsigned int* cnt = slotBase + g * 32;
    unsigned int* rel = slotBase + (32 + g) * 32;
    unsigned int* root = slotBase + 64 * 32;
    unsigned int m = __hip_atomic_fetch_add(cnt, 1u, __ATOMIC_RELAXED,
                                            __HIP_MEMORY_SCOPE_AGENT);
    if (m == gsz - 1u) {                   // last of group -> root
      unsigned int r = __hip_atomic_fetch_add(root, 1u, __ATOMIC_RELAXED,
                                              __HIP_MEMORY_SCOPE_AGENT);
      if (r == 31u) {                      // last group -> broadcast release
#pragma unroll
        for (int gg = 0; gg < 32; ++gg)
          st_dev_u32(slotBase + (32 + gg) * 32, 1u);
      }
    }
    while (!ld_dev_u32(rel))
      __builtin_amdgcn_s_sleep(1);
  }
  __syncthreads();
}

// ---------------- workspace layout (shared host/device) -------------------
struct WSL {
  float* lpostT;
  __half* gx1; __half* gx2;            // fp16 extrinsic planes, PAIR-PACKED:
                                       // u32 at [j*(B/2)+(b>>1)] = cols b,b+1
  unsigned short* gy1; unsigned short* gy2;
  __half* ls1;
  int* inv;
  unsigned int* bars;
  unsigned long long *S1a, *S1b, *T1a, *T1b, *S2a, *S2b, *T2a, *T2b;
};

__host__ __device__ inline WSL ws_layout(char* ws) {
  const size_t KB = (size_t)K_ * B_;
  WSL w; char* p = ws;
  w.lpostT = (float*)p;            p += KB * 4;
  w.gx1    = (__half*)p;           p += KB * 2;
  w.gx2    = (__half*)p;           p += KB * 2;
  w.gy1    = (unsigned short*)p;   p += KB * 2;
  w.gy2    = (unsigned short*)p;   p += KB * 2;
  w.ls1    = (__half*)p;           p += KB * 2;
  w.inv    = (int*)p;              p += (size_t)K_ * 4;
  w.bars   = (unsigned int*)p;     p += (size_t)BARS_U * 4;
  const size_t SB = (size_t)(C_ + 1) * B_;          // ull elements
  w.S1a = (unsigned long long*)p;  p += SB * 8;
  w.S1b = (unsigned long long*)p;  p += SB * 8;
  w.T1a = (unsigned long long*)p;  p += SB * 8;
  w.T1b = (unsigned long long*)p;  p += SB * 8;
  w.S2a = (unsigned long long*)p;  p += SB * 8;
  w.S2b = (unsigned long long*)p;  p += SB * 8;
  w.T2a = (unsigned long long*)p;  p += SB * 8;
  w.T2b = (unsigned long long*)p;  p += SB * 8;
  return w;                                          // ~39 MB total
}

// ---------------- one windowed BCJR half-iteration (linear domain) --------
// DEV: persistent phase. gx/gxother/S-T exterior use sc1 (except gxc: plane
// from prep -> plain). Interior S/T via single-buffered LDS with fp16x8
// codec; the intra-phase __syncthreads (DEV only) orders all boundary reads
// before any boundary writes. lsmapped: phase-1 reads ls rows jmap[i] of ls1
// directly (== old ls2[kv+i], bit-identical; ls2 plane deleted).
template <bool DEV>
__device__ __forceinline__ void half_body(
    const int c,
    const __half* __restrict__ gx,
    const unsigned short* __restrict__ gy,
    const __half* __restrict__ lsloc,
    const int* __restrict__ map,
    __half* __restrict__ gxother,
    float* __restrict__ lpost_out,
    const unsigned long long* __restrict__ Sread,
    unsigned long long* __restrict__ Swrite,
    const unsigned long long* __restrict__ Tread,
    unsigned long long* __restrict__ Twrite,
    const unsigned long long* lds_sr, unsigned long long* lds_sw,
    const unsigned long long* lds_tr, unsigned long long* lds_tw,
    int b, int wmode, int mode, int wrS, bool gxc, bool lsmapped) {
  const int kv = c * L_;
  const int kend = kv + L_;
  const unsigned int* gxp = (const unsigned int*)gx;   // packed [K][B/2]
  const int bh = b >> 1;
  const unsigned int hsel = (b & 1) * 16;              // shift for my half
  const bool gdev = DEV && !gxc;

  // ---- issue ALL independent loads upfront ----
  int jmap[L_];
#pragma unroll
  for (int i = 0; i < L_; ++i) jmap[i] = map[kv + i];     // group-uniform
  float gvx[L_];
  unsigned short rgy[L_];
  __half hls[L_];
#pragma unroll
  for (int i = 0; i < L_; ++i) {
    size_t o2 = (size_t)(kv + i) * (B_ / 2) + bh;
    unsigned int u = gdev ? ld_dev_u32(gxp + o2) : gxp[o2];
    gvx[i] = h2f_bits((unsigned short)(u >> hsel));
    rgy[i] = gy[(size_t)(kv + i) * B_ + b];
  }
  if (mode == 0) {
#pragma unroll
    for (int i = 0; i < L_; ++i) {
      const size_t lrow = lsmapped ? (size_t)jmap[i] : (size_t)(kv + i);
      hls[i] = lsloc[lrow * B_ + b];           // L2-hot coalesced rows
    }
  }
  unsigned long long sA = 0, sB = 0, tA = 0, tB = 0;
  bool s_lds = false, t_lds = false;
  float wfx[W0_], wbx[W0_];
  unsigned short wfy[W0_], wby[W0_];
  if (wmode == 2) {
    if (c > 0) {
      if (DEV && lds_sr) { sA = lds_sr[0]; sB = lds_sr[1]; s_lds = true; }
      else {
        const size_t o = (size_t)c * B_ + b;
        sA = DEV ? ld_dev_u64(Sread + o) : Sread[o];
      }
    }
    if (c < C_ - 1) {
      if (DEV && lds_tr) { tA = lds_tr[0]; tB = lds_tr[1]; t_lds = true; }
      else {
        const size_t o = (size_t)(c + 1) * B_ + b;
        tA = DEV ? ld_dev_u64(Tread + o) : Tread[o];
      }
    }
  } else {
    // warmup gammas, all upfront (wu == W0_ exactly, since kv >= W0_ at c>=1)
    if (c > 0) {
#pragma unroll
      for (int q = 0; q < W0_; ++q) {
        size_t o2 = (size_t)(kv - W0_ + q) * (B_ / 2) + bh;
        unsigned int u = gdev ? ld_dev_u32(gxp + o2) : gxp[o2];
        wfx[q] = h2f_bits((unsigned short)(u >> hsel));
        wfy[q] = gy[(size_t)(kv - W0_ + q) * B_ + b];
      }
    }
    if (c < C_ - 1) {
#pragma unroll
      for (int q = 0; q < W0_; ++q) {
        size_t o2 = (size_t)(kend + W0_ - 1 - q) * (B_ / 2) + bh;
        unsigned int u = gdev ? ld_dev_u32(gxp + o2) : gxp[o2];
        wbx[q] = h2f_bits((unsigned short)(u >> hsel));
        wby[q] = gy[(size_t)(kend + W0_ - 1 - q) * B_ + b];
      }
    }
  }
  // single-buffer hazard fence: all LDS boundary reads above complete in
  // every thread before any thread's boundary write below.
  if (DEV) __syncthreads();

  // ---- valid gammas (gvx kept: needed for extrinsic) ----
  float gc[L_][4];
#pragma unroll
  for (int i = 0; i < L_; ++i) gam_lin(gvx[i], b2f(rgy[i]), gc[i]);

  // ---------------- forward ----------------
  float a[8];
  if (c == 0) {
    a[0] = 1.0f;
#pragma unroll
    for (int s = 1; s < 8; ++s) a[s] = 0.0f;
  } else if (wmode == 0) {
    if (c == 1) {                    // warmup starts at position 0: exact init
      a[0] = 1.0f;
#pragma unroll
      for (int s = 1; s < 8; ++s) a[s] = 0.0f;
    } else {
#pragma unroll
      for (int s = 0; s < 8; ++s) a[s] = 1.0f;
    }
#pragma unroll
    for (int q = 0; q < W0_; ++q) {
      float g[4];
      gam_lin(wfx[q], b2f(wfy[q]), g);
      step_fwd_lin(a, g);
      if (q & 1) renorm_lin(a);
    }
  } else {
    if (s_lds) unpack8_h(sA, sB, a); else unpack8_log8(sA, a);
  }
  // valid region: record alpha, then step (all L steps -> a = alpha(kend))
  float a2d[L_][8];
#pragma unroll
  for (int i = 0; i < L_; ++i) {
#pragma unroll
    for (int s = 0; s < 8; ++s) a2d[i][s] = a[s];
    step_fwd_lin(a, gc[i]);
    if (i & 1) renorm_lin(a);
  }
  if (wrS) {
    if (DEV && lds_sw) {
      pack8_h(a, lds_sw);
    } else {
      unsigned long long v = pack8_log8(a);
      unsigned long long* p = Swrite + (size_t)(c + 1) * B_ + b;
      if (DEV) st_dev_u64(p, v); else *p = v;
    }
  }

  // ---------------- backward + posterior ----------------
  float bt[8];
  if (c == C_ - 1) {
#pragma unroll
    for (int s = 0; s < 8; ++s) bt[s] = 1.0f;    // exact tail init (uniform)
  } else if (wmode == 0) {
#pragma unroll
    for (int s = 0; s < 8; ++s) bt[s] = 1.0f;    // uniform (exact at c=C_-2)
#pragma unroll
    for (int q = 0; q < W0_; ++q) {
      float g[4];
      gam_lin(wbx[q], b2f(wby[q]), g);
      step_bwd_lin(bt, g);
      if (q & 1) renorm_lin(bt);
    }
  } else {
    if (t_lds) unpack8_h(tA, tB, bt); else unpack8_log8(tA, bt);
  }
  // valid region, descending: posterior + extrinsic + beta step
#pragma unroll
  for (int ii = 0; ii < L_; ++ii) {
    const int i = L_ - 1 - ii;
    const float* g = gc[i];
    float s00 = 0.0f, s01 = 0.0f, s10 = 0.0f, s11 = 0.0f;
    float bn[8];
#pragma unroll
    for (int s = 0; s < 8; ++s) {
      const int s0 = s & 1, s1b = (s >> 1) & 1, s2b = (s >> 2) & 1;
      const int f0 = s1b ^ s0, q = s1b ^ s2b;
      float b0 = bt[(f0 << 2) | (s >> 1)];
      float b1 = bt[((f0 ^ 1) << 2) | (s >> 1)];
      float m0 = a2d[i][s] * b0;
      float m1 = a2d[i][s] * b1;
      if (q == 0) { s00 += m0; s10 += m1; } else { s01 += m0; s11 += m1; }
      bn[s] = g[q] * b0 + g[2 + (q ^ 1)] * b1;
    }
    float t0 = g[0] * s00 + g[1] * s01;
    float t1 = g[3] * s10 + g[2] * s11;
    float lpost = LOG2F(fmaxf(t0, 1e-37f)) - LOG2F(fmaxf(t1, 1e-37f));
    if (mode == 0) {
      float le = lpost - gvx[i];                 // lpost - (ls + la)
      unsigned short us = f2h_bits(__half2float(hls[i]) + le);
      // quad-pack with lane partners (jmap row uniform across the group)
      unsigned int po = (unsigned int)__shfl_xor((int)us, 1);
      unsigned int u32v = (b & 1) ? (po | ((unsigned int)us << 16))
                                  : ((unsigned int)us | (po << 16));
      unsigned int uhi = (unsigned int)__shfl_xor((int)u32v, 2);
      if ((b & 3) == 0) {
        unsigned long long v64 =
            (unsigned long long)u32v | ((unsigned long long)uhi << 32);
        unsigned long long* p =
            (unsigned long long*)gxother + ((size_t)jmap[i] * (B_ / 4) + (b >> 2));
        if (DEV) st_dev_u64(p, v64); else *p = v64;
      }
    } else {
      float v = -LN2 * lpost;                    // final value, row perm[kk]
      float* p = lpost_out + ((size_t)jmap[i] * B_ + b);
      if (DEV) st_dev_f32(p, v); else *p = v;    // sc1: read by out-phase
    }
#pragma unroll
    for (int s = 0; s < 8; ++s) bt[s] = bn[s];
    if (ii & 1) renorm_lin(bt);
  }
  if (wrS) {
    if (DEV && lds_tw) {
      pack8_h(bt, lds_tw);
    } else {
      unsigned long long v = pack8_log8(bt);
      unsigned long long* p = Twrite + (size_t)c * B_ + b;
      if (DEV) st_dev_u64(p, v); else *p = v;
    }
  }
}

// ---------------- persistent megakernel (plain launch) --------------------
// Phases: [prep: deinterleave+transpose, sc1 out] -> bar -> 12 half phases
// (interior S/T in single-buffered LDS, fp16x8) -> bar -> out-transpose.
// LDS: one 49.9 KB region aliased across {prep tile, S/T buffers, out tile}.
__global__ __launch_bounds__(1024) void k_fused(const float* __restrict__ inp,
                                                const int* __restrict__ perm,
                                                float* __restrict__ out,
                                                char* __restrict__ ws) {
  WSL w = ws_layout(ws);
  __shared__ __align__(16) char ldsraw[3 * 64 * 65 * 4];   // 49920 B
  const int tid = threadIdx.x;
  const int q = tid >> 8;                    // chunk slot in block
  const int b = tid & 255;
  const int c = blockIdx.x * CPB + q;
  const unsigned int gsz = gridDim.x >> 5;   // blocks per barrier group

  // ---- phase P: prep (fold of k_prep1). All outputs sc1 -> MALL. ----
  {
    float (*tp)[64][65] = (float(*)[64][65])ldsraw;
    for (int t = blockIdx.x; t < NTILE; t += gridDim.x) {
      const int k0 = (t % 96) * 64, b0 = (t / 96) * 64;
      __syncthreads();                       // LDS reuse guard
      const int tk = tid & 63;
      for (int bb = tid >> 6; bb < 64; bb += 16) {
        size_t base = (size_t)(b0 + bb) * (3 * K_) + 3 * (size_t)(k0 + tk);
        tp[0][bb][tk] = inp[base + 0];
        tp[1][bb][tk] = inp[base + 1];
        tp[2][bb][tk] = inp[base + 2];
      }
      __syncthreads();
      const int tb = tid & 63;
      if (!(tb & 1)) {
        for (int kk = tid >> 6; kk < 64; kk += 16) {
          size_t o = (size_t)(k0 + kk) * B_ + (b0 + tb);
          float sv0 = -LOG2E * tp[0][tb][kk];
          float sv1 = -LOG2E * tp[0][tb + 1][kk];
          unsigned int uls = (unsigned int)f2h_bits(sv0) |
                             ((unsigned int)f2h_bits(sv1) << 16);
          unsigned int ug1 = (unsigned int)f2b(-LOG2E * tp[1][tb][kk]) |
                             ((unsigned int)f2b(-LOG2E * tp[1][tb + 1][kk]) << 16);
          unsigned int ug2 = (unsigned int)f2b(-LOG2E * tp[2][tb][kk]) |
                             ((unsigned int)f2b(-LOG2E * tp[2][tb + 1][kk]) << 16);
          st_dev_u32((unsigned int*)w.ls1 + (o >> 1), uls);
          st_dev_u32((unsigned int*)w.gx1 + (o >> 1), uls);  // it0 la=0 plane
          st_dev_u32((unsigned int*)w.gy1 + (o >> 1), ug1);
          st_dev_u32((unsigned int*)w.gy2 + (o >> 1), ug2);
        }
      }
      if (t < 96 && tid < 64)                // inverse permutation
        st_dev_u32((unsigned int*)w.inv + perm[k0 + tid],
                   (unsigned int)(k0 + tid));
    }
  }
  tree_barrier(w.bars + 0 * SLOT_U, gsz);

  // interior S/T slots: [st 0/1][dec 0/1][boundary 0..2][b] x 2 u64 (fp16x8)
  unsigned long long* stbase = (unsigned long long*)ldsraw;
#define STSLOT(st, d, bb) (stbase + ((((st) * 2 + (d)) * 3 + (bb)) * 256 + b) * 2)

  int slot = 1;
  for (int it = 0; it < NITER; ++it) {
    const int pr = it & 1;
    const int wm = (it == 0) ? 0 : 2;
    const int wrS = (it != NITER - 1) ? 1 : 0;
    unsigned long long* S1r = pr ? w.S1b : w.S1a;
    unsigned long long* S1w = pr ? w.S1a : w.S1b;
    unsigned long long* T1r = pr ? w.T1b : w.T1a;
    unsigned long long* T1w = pr ? w.T1a : w.T1b;
    unsigned long long* S2r = pr ? w.S2b : w.S2a;
    unsigned long long* S2w = pr ? w.S2a : w.S2b;
    unsigned long long* T2r = pr ? w.T2b : w.T2a;
    unsigned long long* T2w = pr ? w.T2a : w.T2b;
    // phase 0 (decoder 1): extrinsic -> gx2[inv[kk]]; ls rows kv+i of ls1.
    half_body<true>(c, w.gx1, w.gy1, w.ls1, w.inv, w.gx2, w.lpostT,
                    S1r, S1w, T1r, T1w,
                    (q > 0) ? STSLOT(0, 0, q - 1) : nullptr,
                    (q < 3) ? STSLOT(0, 0, q) : nullptr,
                    (q < 3) ? STSLOT(1, 0, q) : nullptr,
                    (q > 0) ? STSLOT(1, 0, q - 1) : nullptr,
                    b, wm, 0, wrS, it == 0, false);
    tree_barrier(w.bars + slot * SLOT_U, gsz); ++slot;
    // phase 1 (decoder 2): extrinsic -> gx1[perm[kk]]; ls rows jmap of ls1.
    half_body<true>(c, w.gx2, w.gy2, w.ls1, perm, w.gx1, w.lpostT,
                    S2r, S2w, T2r, T2w,
                    (q > 0) ? STSLOT(0, 1, q - 1) : nullptr,
                    (q < 3) ? STSLOT(0, 1, q) : nullptr,
                    (q < 3) ? STSLOT(1, 1, q) : nullptr,
                    (q > 0) ? STSLOT(1, 1, q - 1) : nullptr,
                    b, wm, (it == NITER - 1) ? 1 : 0, wrS, false, true);
    tree_barrier(w.bars + slot * SLOT_U, gsz); ++slot;
  }
#undef STSLOT

  // ---- out-phase: out[b,i] = lpostT[i,b] (sc1-written -> sc1 reads). ----
  float* tt = (float*)ldsraw;                // 64x65 tile
  for (int t = blockIdx.x; t < NTILE; t += gridDim.x) {
    const int i0 = (t >> 2) * 64;
    const int b0 = (t & 3) * 64;
    __syncthreads();                         // LDS reuse guard
    const int tb = tid & 63, iq = tid >> 6;
    for (int ii = iq; ii < 64; ii += 16)
      tt[ii * 65 + tb] =
          ld_dev_f32(w.lpostT + (size_t)(i0 + ii) * B_ + (b0 + tb));
    __syncthreads();
    for (int bb = iq; bb < 64; bb += 16)
      out[(size_t)(b0 + bb) * K_ + (i0 + tb)] = tt[tb * 65 + bb];
  }
}

// ---------------- fallback kernels (proven multi-launch path) -------------
__global__ __launch_bounds__(256, 4) void k_half(
    const __half* __restrict__ gx, const unsigned short* __restrict__ gy,
    const __half* __restrict__ lsloc, const int* __restrict__ map,
    __half* __restrict__ gxother, float* __restrict__ lpost_out,
    const unsigned long long* __restrict__ Sread,
    unsigned long long* __restrict__ Swrite,
    const unsigned long long* __restrict__ Tread,
    unsigned long long* __restrict__ Twrite,
    int wmode, int mode, int wrS, int lsmapped) {
  half_body<false>(blockIdx.x, gx, gy, lsloc, map, gxother, lpost_out,
                   Sread, Swrite, Tread, Twrite,
                   nullptr, nullptr, nullptr, nullptr,
                   threadIdx.x, wmode, mode, wrS, true, lsmapped != 0);
}

__global__ __launch_bounds__(256) void k_out(const float* __restrict__ lpostT,
                                             float* __restrict__ out) {
  __shared__ float t[64][65];
  const int tid = threadIdx.x;
  const int i0 = blockIdx.x * 64, b0 = blockIdx.y * 64;
  const int tb = tid & 63, iq = tid >> 6;
  for (int ii = iq; ii < 64; ii += 4) {
    t[ii][tb] = lpostT[(size_t)(i0 + ii) * B_ + (b0 + tb)];
  }
  __syncthreads();
  const int ik = tid & 63, bq = tid >> 6;
  for (int bb = bq; bb < 64; bb += 4) {
    out[(size_t)(b0 + bb) * K_ + (i0 + ik)] = t[ik][bb];
  }
}

// prep for the FALLBACK path only (plain stores, kernel-boundary publish)
__global__ __launch_bounds__(256) void k_prep1(const float* __restrict__ inp,
                                               const int* __restrict__ perm,
                                               __half* __restrict__ gx1,
                                               __half* __restrict__ ls1,
                                               unsigned short* __restrict__ gy1,
                                               unsigned short* __restrict__ gy2,
                                               int* __restrict__ inv) {
  __shared__ float t[3][64][65];
  const int tid = threadIdx.x;
  const int k0 = blockIdx.x * 64, b0 = blockIdx.y * 64;
  const int tk = tid & 63, tq = tid >> 6;
  for (int bb = tq; bb < 64; bb += 4) {
    size_t base = (size_t)(b0 + bb) * (3 * K_) + 3 * (size_t)(k0 + tk);
    t[0][bb][tk] = inp[base + 0];
    t[1][bb][tk] = inp[base + 1];
    t[2][bb][tk] = inp[base + 2];
  }
  __syncthreads();
  const int tb = tid & 63, kq = tid >> 6;
  for (int kk = kq; kk < 64; kk += 4) {
    size_t o = (size_t)(k0 + kk) * B_ + (b0 + tb);
    float sv = -LOG2E * t[0][tb][kk];
    ls1[o] = __float2half(sv);
    gy1[o] = f2b(-LOG2E * t[1][tb][kk]);
    gy2[o] = f2b(-LOG2E * t[2][tb][kk]);
    if (!(tb & 1)) {
      float sv1 = -LOG2E * t[0][tb + 1][kk];
      unsigned int u = (unsigned int)f2h_bits(sv) |
                       ((unsigned int)f2h_bits(sv1) << 16);
      ((unsigned int*)gx1)[o >> 1] = u;
    }
  }
  if (blockIdx.y == 0 && tid < 64) {
    const int j = k0 + tid;
    inv[perm[j]] = j;
  }
}

// ---------------- launch ---------------------------------------------------
static void launch_fallback(const float* inp, const int* perm, float* out,
                            char* wsb, hipStream_t stream) {
  WSL w = ws_layout(wsb);
  k_prep1<<<dim3(K_ / 64, B_ / 64), 256, 0, stream>>>(
      inp, perm, w.gx1, w.ls1, w.gy1, w.gy2, w.inv);
  for (int it = 0; it < NITER; ++it) {
    const int pr = it & 1;
    const int wm = (it == 0) ? 0 : 2;
    const int wrS = (it != NITER - 1) ? 1 : 0;
    unsigned long long* S1r = pr ? w.S1b : w.S1a;
    unsigned long long* S1w = pr ? w.S1a : w.S1b;
    unsigned long long* T1r = pr ? w.T1b : w.T1a;
    unsigned long long* T1w = pr ? w.T1a : w.T1b;
    unsigned long long* S2r = pr ? w.S2b : w.S2a;
    unsigned long long* S2w = pr ? w.S2a : w.S2b;
    unsigned long long* T2r = pr ? w.T2b : w.T2a;
    unsigned long long* T2w = pr ? w.T2a : w.T2b;
    k_half<<<C_, 256, 0, stream>>>(w.gx1, w.gy1, w.ls1, w.inv, w.gx2,
                                   w.lpostT, S1r, S1w, T1r, T1w, wm, 0, wrS,
                                   0);
    k_half<<<C_, 256, 0, stream>>>(w.gx2, w.gy2, w.ls1, perm, w.gx1,
                                   w.lpostT, S2r, S2w, T2r, T2w, wm,
                                   (it == NITER - 1) ? 1 : 0, wrS, 1);
  }
  k_out<<<dim3(K_ / 64, B_ / 64), 256, 0, stream>>>(w.lpostT, out);
}

extern "C" void kernel_launch(void* const* d_in, const int* in_sizes, int n_in,
                              void* d_out, int out_size, void* d_ws, size_t ws_size,
                              hipStream_t stream) {
  (void)in_sizes; (void)n_in; (void)out_size; (void)ws_size;
  const float* inp = (const float*)d_in[0];
  const int* perm = (const int*)d_in[1];
  float* out = (float*)d_out;
  char* wsb = (char*)d_ws;
  WSL w = ws_layout(wsb);

  // mode: 0 = undecided, 1 = persistent plain-launch, 2 = fallback.
  // Co-residency: GRID=256 1024-thread blocks; cap = min(2048 thr/CU,
  // 160KB/50KB LDS) >= 1 block/CU -> 256 slots. No cooperative API.
  static int g_mode = 0;

  if (g_mode == 0) {
    int nb = 0;
    if (hipOccupancyMaxActiveBlocksPerMultiprocessor(&nb, k_fused, 1024, 0)
            != hipSuccess)
      nb = 0;
    int ncu = 0;
    hipDeviceProp_t prop;
    int dev = 0;
    (void)hipGetDevice(&dev);
    if (hipGetDeviceProperties(&prop, dev) == hipSuccess)
      ncu = prop.multiProcessorCount;
    g_mode = ((long long)nb * ncu >= GRID && (GRID % 32) == 0) ? 1 : 2;
  }

  if (g_mode == 1) {
    // zero barrier slots (kernel-boundary publish orders it before k_fused)
    (void)hipMemsetAsync(w.bars, 0, (size_t)BARS_U * 4, stream);
    k_fused<<<GRID, 1024, 0, stream>>>(inp, perm, out, wsb);
  } else {
    launch_fallback(inp, perm, out, wsb, stream);
  }
}